// Round 1
// baseline (3626.028 us; speedup 1.0000x reference)
//
#include <hip/hip_runtime.h>
#include <hip/hip_bf16.h>
#include <math.h>

#define BB   8
#define CCH  192
#define OCN  576
#define HWD  128
#define HWN  16384
#define NH   4
#define CHD  48
#define C51  51

typedef __hip_bfloat16 bf16;

__device__ __forceinline__ float bfbits2f(unsigned int u16) {
  union { unsigned int i; float f; } v; v.i = u16 << 16; return v.f;
}

// ---------------- K0: svp 1x1 conv (3 -> 12) + sum-of-squares ----------------
__global__ __launch_bounds__(256) void k_svp(
    const float* __restrict__ svp_fea, const float* __restrict__ svp_w,
    float* __restrict__ svp_q, float* __restrict__ ssq_svp)
{
  const int b = blockIdx.y;
  const int n = blockIdx.x * 256 + threadIdx.x;
  const float* fb = svp_fea + (size_t)b * 3 * HWN;
  const float f0 = fb[n], f1 = fb[HWN + n], f2 = fb[2 * HWN + n];
  float* ob = svp_q + (size_t)b * 12 * HWN + n;
  #pragma unroll
  for (int r = 0; r < 12; ++r) {
    float o = svp_w[r*3]*f0 + svp_w[r*3+1]*f1 + svp_w[r*3+2]*f2;
    ob[(size_t)r * HWN] = o;
    float v = o * o;
    #pragma unroll
    for (int off = 32; off >= 1; off >>= 1) v += __shfl_down(v, off, 64);
    if ((threadIdx.x & 63) == 0) atomicAdd(&ssq_svp[b*12 + r], v);
  }
}

// ------- K1: fused 1x1 conv (192->576) + 3x3 depthwise, bf16 output ---------
// block = (tile 16x16, b). 384 threads. Halo tile 18x18=324 recomputed.
__global__ __launch_bounds__(384) void k_qkv_dw(
    const float* __restrict__ x, const float* __restrict__ qkv_w,
    const float* __restrict__ dw_w, bf16* __restrict__ qkv)
{
  __shared__ float xs[16 * 324];   // x chunk [16c][324px]
  __shared__ float tmp[32 * 324];  // 1x1 result for ocg [32oc][324px]
  __shared__ float wl[16 * 32];    // qkv_w chunk transposed [c][oc]
  __shared__ float dww[32 * 9];    // dw weights
  const int b = blockIdx.y;
  const int tile = blockIdx.x;
  const int ty0 = (tile >> 3) << 4, tx0 = (tile & 7) << 4;
  const int t = threadIdx.x;
  const int pxq = t % 96, ocq = t / 96;   // 96 px-quads x 4 oc-groups
  const int px0 = pxq * 4;
  const float* xb = x + (size_t)b * CCH * HWN;
  for (int ocg = 0; ocg < 18; ++ocg) {
    const int oc0 = ocg * 32;
    float acc[8][4];
    #pragma unroll
    for (int i = 0; i < 8; ++i)
      #pragma unroll
      for (int j = 0; j < 4; ++j) acc[i][j] = 0.f;
    for (int cc = 0; cc < 12; ++cc) {
      const int c0 = cc * 16;
      __syncthreads();
      for (int idx = t; idx < 16 * 324; idx += 384) {
        int c = idx / 324, p = idx - c * 324;
        int py = p / 18, px = p - py * 18;
        int gy = ty0 + py - 1, gx = tx0 + px - 1;
        float v = 0.f;
        if ((unsigned)gy < 128u && (unsigned)gx < 128u)
          v = xb[(size_t)(c0 + c) * HWN + gy * HWD + gx];
        xs[idx] = v;
      }
      for (int idx = t; idx < 512; idx += 384) {
        int c = idx >> 5, oc = idx & 31;
        wl[idx] = qkv_w[(oc0 + oc) * CCH + c0 + c];
      }
      __syncthreads();
      if (px0 < 324) {
        #pragma unroll
        for (int c = 0; c < 16; ++c) {
          float4 xv = *(const float4*)&xs[c * 324 + px0];
          float4 w0 = *(const float4*)&wl[c * 32 + ocq * 8];
          float4 w1 = *(const float4*)&wl[c * 32 + ocq * 8 + 4];
          float wv[8] = {w0.x,w0.y,w0.z,w0.w,w1.x,w1.y,w1.z,w1.w};
          float xvv[4] = {xv.x,xv.y,xv.z,xv.w};
          #pragma unroll
          for (int i = 0; i < 8; ++i)
            #pragma unroll
            for (int j = 0; j < 4; ++j)
              acc[i][j] += wv[i] * xvv[j];
        }
      }
    }
    __syncthreads();
    if (px0 < 324) {
      #pragma unroll
      for (int i = 0; i < 8; ++i) {
        float4 st = {acc[i][0], acc[i][1], acc[i][2], acc[i][3]};
        *(float4*)&tmp[(ocq * 8 + i) * 324 + px0] = st;
      }
    }
    for (int idx = t; idx < 288; idx += 384) dww[idx] = dw_w[oc0 * 9 + idx];
    __syncthreads();
    if (t < 256) {
      const int py = t >> 4, px = t & 15;
      bf16* op = qkv + ((size_t)b * OCN + oc0) * HWN + (ty0 + py) * HWD + tx0 + px;
      #pragma unroll 4
      for (int oc = 0; oc < 32; ++oc) {
        const float* tp = &tmp[oc * 324 + py * 18 + px];
        const float* wp = &dww[oc * 9];
        float o = wp[0]*tp[0]  + wp[1]*tp[1]  + wp[2]*tp[2]
                + wp[3]*tp[18] + wp[4]*tp[19] + wp[5]*tp[20]
                + wp[6]*tp[36] + wp[7]*tp[37] + wp[8]*tp[38];
        op[(size_t)oc * HWN] = __float2bfloat16(o);
      }
    }
  }
}

// ---------- K2: per-(b,channel) sum of squares over HW for q,k --------------
__global__ __launch_bounds__(256) void k_norm(
    const bf16* __restrict__ qkv, float* __restrict__ ssq_qk)
{
  const int b = blockIdx.y, ch = blockIdx.x;  // ch in [0,384)
  const unsigned short* p = (const unsigned short*)qkv + ((size_t)b * OCN + ch) * HWN;
  const int t = threadIdx.x;
  float s = 0.f;
  for (int i = t * 8; i < HWN; i += 256 * 8) {
    uint4 u = *(const uint4*)(p + i);
    unsigned int ua[4] = {u.x, u.y, u.z, u.w};
    #pragma unroll
    for (int k = 0; k < 4; ++k) {
      float a = bfbits2f(ua[k] & 0xffffu);
      float c = bfbits2f(ua[k] >> 16);
      s += a * a + c * c;
    }
  }
  #pragma unroll
  for (int off = 32; off >= 1; off >>= 1) s += __shfl_down(s, off, 64);
  __shared__ float wsum[4];
  if ((t & 63) == 0) wsum[t >> 6] = s;
  __syncthreads();
  if (t == 0) ssq_qk[b * 384 + ch] = wsum[0] + wsum[1] + wsum[2] + wsum[3];
}

// ---------- K3: raw Gram G[b,h,51,48] = qcat @ k^T over HW (chunked) --------
__global__ __launch_bounds__(256) void k_gram(
    const bf16* __restrict__ qkv, const float* __restrict__ svp_q,
    float* __restrict__ G)
{
  __shared__ float kcs[48 * 132];
  __shared__ float qcs[C51 * 132];
  const int chunk = blockIdx.x, h = blockIdx.y, b = blockIdx.z;
  const int t = threadIdx.x;
  const int tq = t >> 4, td = t & 15;
  const int c0 = tq * 4, d0 = td * 3;
  const bool act = (tq < 13);
  float acc[4][3];
  #pragma unroll
  for (int i = 0; i < 4; ++i)
    #pragma unroll
    for (int j = 0; j < 3; ++j) acc[i][j] = 0.f;
  const unsigned short* qb = (const unsigned short*)qkv + ((size_t)b*OCN + h*CHD)*HWN;
  const unsigned short* kb = (const unsigned short*)qkv + ((size_t)b*OCN + 192 + h*CHD)*HWN;
  const float* sb = svp_q + ((size_t)b*12 + h*3)*HWN;
  for (int it = 0; it < 8; ++it) {
    const int n0 = chunk * 1024 + it * 128;
    __syncthreads();
    for (int idx = t; idx < 99 * 128; idx += 256) {
      int row = idx >> 7, col = idx & 127;
      if (row < 48) {
        kcs[row*132 + col] = bfbits2f((unsigned int)kb[(size_t)row*HWN + n0 + col]);
      } else {
        int qr = row - 48;
        float v = (qr < 48) ? bfbits2f((unsigned int)qb[(size_t)qr*HWN + n0 + col])
                            : sb[(size_t)(qr - 48)*HWN + n0 + col];
        qcs[qr*132 + col] = v;
      }
    }
    __syncthreads();
    if (act) {
      for (int n = 0; n < 128; n += 4) {
        float4 kv0 = *(const float4*)&kcs[(d0+0)*132 + n];
        float4 kv1 = *(const float4*)&kcs[(d0+1)*132 + n];
        float4 kv2 = *(const float4*)&kcs[(d0+2)*132 + n];
        #pragma unroll
        for (int i = 0; i < 4; ++i) {
          if (c0 + i < C51) {
            float4 qv = *(const float4*)&qcs[(c0+i)*132 + n];
            acc[i][0] += qv.x*kv0.x + qv.y*kv0.y + qv.z*kv0.z + qv.w*kv0.w;
            acc[i][1] += qv.x*kv1.x + qv.y*kv1.y + qv.z*kv1.z + qv.w*kv1.w;
            acc[i][2] += qv.x*kv2.x + qv.y*kv2.y + qv.z*kv2.z + qv.w*kv2.w;
          }
        }
      }
    }
  }
  float* Gb = G + (size_t)(b*NH + h) * C51 * 48;
  if (act) {
    #pragma unroll
    for (int i = 0; i < 4; ++i) {
      if (c0 + i < C51) {
        #pragma unroll
        for (int j = 0; j < 3; ++j)
          atomicAdd(&Gb[(c0+i)*48 + d0 + j], acc[i][j]);
      }
    }
  }
}

// ---- K4: normalize+softmax -> attn; fold with proj_w -> W2[b,192,192] ------
__global__ __launch_bounds__(256) void k_attn_fold(
    const float* __restrict__ G, const float* __restrict__ ssq_qk,
    const float* __restrict__ ssq_svp, const float* __restrict__ temperature,
    const float* __restrict__ proj_w, float* __restrict__ W2)
{
  __shared__ float A[C51 * 48];
  __shared__ float qinv[C51];
  __shared__ float kinv[48];
  const int h = blockIdx.x, b = blockIdx.y;
  const int t = threadIdx.x;
  const float* Gb = G + (size_t)(b*NH + h) * C51 * 48;
  if (t < 48) kinv[t] = 1.f / fmaxf(sqrtf(ssq_qk[b*384 + 192 + h*48 + t]), 1e-12f);
  if (t >= 64 && t < 64 + C51) {
    int c = t - 64;
    float ss = (c < 48) ? ssq_qk[b*384 + h*48 + c] : ssq_svp[b*12 + h*3 + (c - 48)];
    qinv[c] = 1.f / fmaxf(sqrtf(ss), 1e-12f);
  }
  for (int idx = t; idx < C51*48; idx += 256) A[idx] = Gb[idx];
  __syncthreads();
  const float temp = temperature[h];
  if (t < C51) {
    float row[48];
    float m = -1e30f;
    const float qi = qinv[t] * temp;
    #pragma unroll
    for (int d = 0; d < 48; ++d) {
      float l = A[t*48 + d] * qi * kinv[d];
      row[d] = l; m = fmaxf(m, l);
    }
    float s = 0.f;
    #pragma unroll
    for (int d = 0; d < 48; ++d) { row[d] = expf(row[d] - m); s += row[d]; }
    const float inv = 1.f / s;
    #pragma unroll
    for (int d = 0; d < 48; ++d) A[t*48 + d] = row[d] * inv;
  }
  __syncthreads();
  for (int idx = t; idx < 192*48; idx += 256) {
    int o = idx / 48, d = idx - o*48;
    const float* pw = proj_w + o*204 + C51*h;
    float s = 0.f;
    #pragma unroll
    for (int c = 0; c < C51; ++c) s += pw[c] * A[c*48 + d];
    W2[((size_t)b*CCH + o)*CCH + h*48 + d] = s;
  }
}

// ---------- K5: out[b] = W2[b] (192x192, LDS) @ v (bf16) --------------------
__global__ __launch_bounds__(256) void k_out(
    const bf16* __restrict__ qkv, const float* __restrict__ W2,
    float* __restrict__ out)
{
  __shared__ float W2s[96 * 192];
  const int b = blockIdx.z, oh = blockIdx.y;
  const int n0 = blockIdx.x * 512;
  const int t = threadIdx.x;
  const float* wsrc = W2 + ((size_t)b*CCH + oh*96)*CCH;
  for (int idx = t; idx < 96*192/4; idx += 256)
    ((float4*)W2s)[idx] = ((const float4*)wsrc)[idx];
  __syncthreads();
  const unsigned short* vb = (const unsigned short*)qkv
        + ((size_t)b*OCN + 384)*HWN + n0 + 2*t;
  #pragma unroll 1
  for (int og = 0; og < 2; ++og) {
    float acc0[48], acc1[48];
    #pragma unroll
    for (int o = 0; o < 48; ++o) { acc0[o] = 0.f; acc1[o] = 0.f; }
    for (int j4 = 0; j4 < 192; j4 += 4) {
      float vx[4], vy[4];
      #pragma unroll
      for (int jj = 0; jj < 4; ++jj) {
        unsigned int u = *(const unsigned int*)(vb + (size_t)(j4 + jj)*HWN);
        vx[jj] = bfbits2f(u & 0xffffu);
        vy[jj] = bfbits2f(u >> 16);
      }
      const float* wrow = &W2s[og*48*192 + j4];
      #pragma unroll
      for (int o = 0; o < 48; ++o) {
        float4 w = *(const float4*)(wrow + o*192);
        acc0[o] += w.x*vx[0] + w.y*vx[1] + w.z*vx[2] + w.w*vx[3];
        acc1[o] += w.x*vy[0] + w.y*vy[1] + w.z*vy[2] + w.w*vy[3];
      }
    }
    float* ob = out + ((size_t)b*CCH + oh*96 + og*48)*HWN + n0 + 2*t;
    #pragma unroll
    for (int o = 0; o < 48; ++o) {
      float2 st = {acc0[o], acc1[o]};
      *(float2*)(ob + (size_t)o*HWN) = st;
    }
  }
}

// ---------------------------------------------------------------------------
extern "C" void kernel_launch(void* const* d_in, const int* in_sizes, int n_in,
                              void* d_out, int out_size, void* d_ws, size_t ws_size,
                              hipStream_t stream)
{
  const float* x       = (const float*)d_in[0];
  const float* svp_fea = (const float*)d_in[1];
  const float* qkv_w   = (const float*)d_in[2];
  const float* dw_w    = (const float*)d_in[3];
  const float* svp_w   = (const float*)d_in[4];
  const float* proj_w  = (const float*)d_in[5];
  const float* temp    = (const float*)d_in[6];
  float* outp = (float*)d_out;

  char* ws = (char*)d_ws;
  const size_t off_qkv    = 0;
  const size_t off_svpq   = off_qkv   + (size_t)BB*OCN*HWN*2;   // 150,994,944
  const size_t off_ssqqk  = off_svpq  + (size_t)BB*12*HWN*4;    // +6,291,456
  const size_t off_ssqsvp = off_ssqqk + (size_t)BB*384*4;       // +12,288
  const size_t off_G      = off_ssqsvp+ (size_t)BB*12*4;        // +384
  const size_t off_W2     = off_G     + (size_t)BB*NH*C51*48*4; // +313,344

  bf16*  qkv     = (bf16*)(ws + off_qkv);
  float* svp_q   = (float*)(ws + off_svpq);
  float* ssq_qk  = (float*)(ws + off_ssqqk);
  float* ssq_svp = (float*)(ws + off_ssqsvp);
  float* G       = (float*)(ws + off_G);
  float* W2      = (float*)(ws + off_W2);

  // zero the atomic accumulators (ssq_svp + G are contiguous)
  hipMemsetAsync(ws + off_ssqsvp, 0, (size_t)BB*12*4 + (size_t)BB*NH*C51*48*4, stream);

  k_svp      <<<dim3(64, BB),    256, 0, stream>>>(svp_fea, svp_w, svp_q, ssq_svp);
  k_qkv_dw   <<<dim3(64, BB),    384, 0, stream>>>(x, qkv_w, dw_w, qkv);
  k_norm     <<<dim3(384, BB),   256, 0, stream>>>(qkv, ssq_qk);
  k_gram     <<<dim3(16, NH, BB),256, 0, stream>>>(qkv, svp_q, G);
  k_attn_fold<<<dim3(NH, BB),    256, 0, stream>>>(G, ssq_qk, ssq_svp, temp, proj_w, W2);
  k_out      <<<dim3(32, 2, BB), 256, 0, stream>>>(qkv, W2, outp);
}

// Round 2
// 900.475 us; speedup vs baseline: 4.0268x; 4.0268x over previous
//
#include <hip/hip_runtime.h>
#include <hip/hip_bf16.h>
#include <math.h>

#define BB   8
#define CCH  192
#define OCN  576
#define HWD  128
#define HWN  16384
#define NH   4
#define CHD  48
#define C51  51

typedef __hip_bfloat16 bf16;
typedef __attribute__((ext_vector_type(8))) short short8;
typedef __attribute__((ext_vector_type(4))) float f32x4;

__device__ __forceinline__ float bfbits2f(unsigned int u16) {
  union { unsigned int i; float f; } v; v.i = u16 << 16; return v.f;
}
__device__ __forceinline__ unsigned short f2bfbits(float f) {
  __hip_bfloat16 h = __float2bfloat16(f);
  return *(unsigned short*)&h;
}
__device__ __forceinline__ void stage16(const void* g, void* l) {
  __builtin_amdgcn_global_load_lds(
      (const __attribute__((address_space(1))) void*)g,
      (__attribute__((address_space(3))) void*)l, 16, 0, 0);
}

// ---------------- K0: svp 1x1 conv (3 -> 12) + sum-of-squares ----------------
__global__ __launch_bounds__(256) void k_svp(
    const float* __restrict__ svp_fea, const float* __restrict__ svp_w,
    float* __restrict__ svp_q, float* __restrict__ ssq_svp)
{
  const int b = blockIdx.y;
  const int n = blockIdx.x * 256 + threadIdx.x;
  const float* fb = svp_fea + (size_t)b * 3 * HWN;
  const float f0 = fb[n], f1 = fb[HWN + n], f2 = fb[2 * HWN + n];
  float* ob = svp_q + (size_t)b * 12 * HWN + n;
  #pragma unroll
  for (int r = 0; r < 12; ++r) {
    float o = svp_w[r*3]*f0 + svp_w[r*3+1]*f1 + svp_w[r*3+2]*f2;
    ob[(size_t)r * HWN] = o;
    float v = o * o;
    #pragma unroll
    for (int off = 32; off >= 1; off >>= 1) v += __shfl_down(v, off, 64);
    if ((threadIdx.x & 63) == 0) atomicAdd(&ssq_svp[b*12 + r], v);
  }
}

// ---------------- K0b: cast qkv_w (576x192 f32) -> bf16 ---------------------
__global__ __launch_bounds__(256) void k_castw(
    const float* __restrict__ w, unsigned short* __restrict__ wb)
{
  const int i = (blockIdx.x * 256 + threadIdx.x) * 4;
  float4 v = *(const float4*)(w + i);
  union { uint2 u; unsigned short s[4]; } pk;
  pk.s[0] = f2bfbits(v.x); pk.s[1] = f2bfbits(v.y);
  pk.s[2] = f2bfbits(v.z); pk.s[3] = f2bfbits(v.w);
  *(uint2*)(wb + i) = pk.u;
}

// ------- K0c: transpose-cast x [b][192][HW] f32 -> xt [b][HW][192] bf16 -----
__global__ __launch_bounds__(256) void k_xt(
    const float* __restrict__ x, unsigned short* __restrict__ xt)
{
  __shared__ unsigned short lsT[64][36];
  const int b = blockIdx.z;
  const int c0 = blockIdx.y * 32, n0 = blockIdx.x * 64;
  const int t = threadIdx.x;
  {
    const int c = t >> 3, ns = (t & 7) * 8;
    const float* src = x + ((size_t)(b * CCH + c0 + c)) * HWN + n0 + ns;
    float4 v0 = *(const float4*)src;
    float4 v1 = *(const float4*)(src + 4);
    float vv[8] = {v0.x,v0.y,v0.z,v0.w,v1.x,v1.y,v1.z,v1.w};
    #pragma unroll
    for (int i = 0; i < 8; ++i) lsT[ns + i][c] = f2bfbits(vv[i]);
  }
  __syncthreads();
  {
    const int n = t >> 2, cs = (t & 3) * 8;
    union { uint4 u; unsigned short s[8]; } pk;
    #pragma unroll
    for (int i = 0; i < 8; ++i) pk.s[i] = lsT[n][cs + i];
    *(uint4*)(xt + ((size_t)(b * HWN + n0 + n)) * CCH + c0 + cs) = pk.u;
  }
}

// ---------- K1: qkv1[b][576][HW] = W(bf16) @ x(bf16), MFMA 16x16x32 ---------
// block: 256 thr (4 waves, 2m x 2n), BN=64 cols, loops 6 m-chunks of 96 rows.
// LDS swizzle: granule(16B) index ^= (row&7) within 8-granule groups, applied
// on BOTH the global_load_lds source and the ds_read address (rule 21).
__global__ __launch_bounds__(256) void k_gemm(
    const unsigned short* __restrict__ xt, const unsigned short* __restrict__ wb,
    unsigned short* __restrict__ qkv1)
{
  __shared__ unsigned short Xs[64 * CCH];
  __shared__ unsigned short Ws[96 * CCH];
  const int b = blockIdx.y;
  const int n0 = blockIdx.x * 64;
  const int t = threadIdx.x;
  const int lane = t & 63, wave = t >> 6;
  const int wm = wave >> 1, wn = wave & 1;
  const int lq = lane >> 4, lr = lane & 15;
  const unsigned short* xtb = xt + ((size_t)b * HWN + n0) * CCH;

  // stage X tile [64 n][192 k] (24 KB, contiguous in xt) once
  #pragma unroll
  for (int i = 0; i < 6; ++i) {
    int chunk = wave * 6 + i;
    int d = chunk * 64 + lane;            // dest 16B-granule
    int row = d / 24, kg = d % 24;
    int skg = (kg & ~7) | ((kg & 7) ^ (row & 7));
    stage16(xtb + (size_t)row * CCH + skg * 8, &Xs[0] + chunk * 512);
  }

  for (int mc = 0; mc < 6; ++mc) {
    const unsigned short* wsrc = wb + (size_t)mc * 96 * CCH;
    #pragma unroll
    for (int i = 0; i < 9; ++i) {
      int chunk = wave * 9 + i;
      int d = chunk * 64 + lane;
      int row = d / 24, kg = d % 24;
      int skg = (kg & ~7) | ((kg & 7) ^ (row & 7));
      stage16(wsrc + (size_t)row * CCH + skg * 8, &Ws[0] + chunk * 512);
    }
    asm volatile("s_waitcnt vmcnt(0)" ::: "memory");
    __syncthreads();

    f32x4 acc[3][2];
    #pragma unroll
    for (int mf = 0; mf < 3; ++mf)
      #pragma unroll
      for (int nf = 0; nf < 2; ++nf) acc[mf][nf] = (f32x4)0.f;

    #pragma unroll
    for (int ks = 0; ks < 6; ++ks) {
      const int gk = ks * 4 + lq;
      short8 a[3], bb[2];
      #pragma unroll
      for (int mf = 0; mf < 3; ++mf) {
        int r = wm * 48 + mf * 16 + lr;
        int sg = (gk & ~7) | ((gk & 7) ^ (r & 7));
        a[mf] = *(const short8*)&Ws[r * CCH + sg * 8];
      }
      #pragma unroll
      for (int nf = 0; nf < 2; ++nf) {
        int r = wn * 32 + nf * 16 + lr;
        int sg = (gk & ~7) | ((gk & 7) ^ (r & 7));
        bb[nf] = *(const short8*)&Xs[r * CCH + sg * 8];
      }
      #pragma unroll
      for (int mf = 0; mf < 3; ++mf)
        #pragma unroll
        for (int nf = 0; nf < 2; ++nf)
          acc[mf][nf] = __builtin_amdgcn_mfma_f32_16x16x32_bf16(
              a[mf], bb[nf], acc[mf][nf], 0, 0, 0);
    }

    unsigned short* ob = qkv1 + ((size_t)b * OCN + mc * 96 + wm * 48) * HWN
                         + n0 + wn * 32;
    #pragma unroll
    for (int mf = 0; mf < 3; ++mf)
      #pragma unroll
      for (int nf = 0; nf < 2; ++nf)
        #pragma unroll
        for (int r = 0; r < 4; ++r) {
          int m = mf * 16 + lq * 4 + r;
          int n = nf * 16 + lr;
          ob[(size_t)m * HWN + n] = f2bfbits(acc[mf][nf][r]);
        }
    __syncthreads();
  }
}

// ---------- K1b: depthwise 3x3 conv, bf16 -> bf16 ---------------------------
__global__ __launch_bounds__(256) void k_dw(
    const unsigned short* __restrict__ qkv1, const float* __restrict__ dw_w,
    unsigned short* __restrict__ qkv)
{
  __shared__ unsigned short ls[34][144];  // data cols 8..135, zero cols 7/136
  const int b = blockIdx.z, c = blockIdx.y, slab = blockIdx.x;
  const int r0 = slab * 32;
  const int t = threadIdx.x;
  const unsigned short* src = qkv1 + ((size_t)b * OCN + c) * HWN;
  for (int g = t; g < 544; g += 256) {
    int row = g >> 4, kc = g & 15;
    int grow = r0 + row - 1;
    uint4 v = make_uint4(0u, 0u, 0u, 0u);
    if ((unsigned)grow < 128u) v = *(const uint4*)(src + grow * HWD + kc * 8);
    *(uint4*)&ls[row][8 + kc * 8] = v;
  }
  if (t < 68) { int row = t >> 1; ls[row][7 + (t & 1) * 129] = 0; }
  __syncthreads();
  float w[9];
  #pragma unroll
  for (int i = 0; i < 9; ++i) w[i] = dw_w[c * 9 + i];
  const int cg = t & 15, rg = t >> 4;
  unsigned short* dst = qkv + ((size_t)b * OCN + c) * HWN;
  #pragma unroll
  for (int e = 0; e < 2; ++e) {
    int ro = rg * 2 + e;
    float acc[8];
    #pragma unroll
    for (int i = 0; i < 8; ++i) acc[i] = 0.f;
    #pragma unroll
    for (int j = 0; j < 3; ++j) {
      float v[10];
      #pragma unroll
      for (int i = 0; i < 10; ++i) v[i] = bfbits2f(ls[ro + j][7 + cg * 8 + i]);
      #pragma unroll
      for (int i = 0; i < 8; ++i)
        acc[i] += w[j*3]*v[i] + w[j*3+1]*v[i+1] + w[j*3+2]*v[i+2];
    }
    union { uint4 u; unsigned short s[8]; } pk;
    #pragma unroll
    for (int i = 0; i < 8; ++i) pk.s[i] = f2bfbits(acc[i]);
    *(uint4*)(dst + (size_t)(r0 + ro) * HWD + cg * 8) = pk.u;
  }
}

// ---------- K2: per-(b,channel) sum of squares over HW for q,k --------------
__global__ __launch_bounds__(256) void k_norm(
    const bf16* __restrict__ qkv, float* __restrict__ ssq_qk)
{
  const int b = blockIdx.y, ch = blockIdx.x;  // ch in [0,384)
  const unsigned short* p = (const unsigned short*)qkv + ((size_t)b * OCN + ch) * HWN;
  const int t = threadIdx.x;
  float s = 0.f;
  for (int i = t * 8; i < HWN; i += 256 * 8) {
    uint4 u = *(const uint4*)(p + i);
    unsigned int ua[4] = {u.x, u.y, u.z, u.w};
    #pragma unroll
    for (int k = 0; k < 4; ++k) {
      float a = bfbits2f(ua[k] & 0xffffu);
      float c = bfbits2f(ua[k] >> 16);
      s += a * a + c * c;
    }
  }
  #pragma unroll
  for (int off = 32; off >= 1; off >>= 1) s += __shfl_down(s, off, 64);
  __shared__ float wsum[4];
  if ((t & 63) == 0) wsum[t >> 6] = s;
  __syncthreads();
  if (t == 0) ssq_qk[b * 384 + ch] = wsum[0] + wsum[1] + wsum[2] + wsum[3];
}

// ---------- K3: raw Gram G[b,h,51,48] = qcat @ k^T over HW (chunked) --------
__global__ __launch_bounds__(256) void k_gram(
    const bf16* __restrict__ qkv, const float* __restrict__ svp_q,
    float* __restrict__ G)
{
  __shared__ float kcs[48 * 132];
  __shared__ float qcs[C51 * 132];
  const int chunk = blockIdx.x, h = blockIdx.y, b = blockIdx.z;
  const int t = threadIdx.x;
  const int tq = t >> 4, td = t & 15;
  const int c0 = tq * 4, d0 = td * 3;
  const bool act = (tq < 13);
  float acc[4][3];
  #pragma unroll
  for (int i = 0; i < 4; ++i)
    #pragma unroll
    for (int j = 0; j < 3; ++j) acc[i][j] = 0.f;
  const unsigned short* qb = (const unsigned short*)qkv + ((size_t)b*OCN + h*CHD)*HWN;
  const unsigned short* kb = (const unsigned short*)qkv + ((size_t)b*OCN + 192 + h*CHD)*HWN;
  const float* sb = svp_q + ((size_t)b*12 + h*3)*HWN;
  for (int it = 0; it < 8; ++it) {
    const int n0 = chunk * 1024 + it * 128;
    __syncthreads();
    for (int idx = t; idx < 99 * 128; idx += 256) {
      int row = idx >> 7, col = idx & 127;
      if (row < 48) {
        kcs[row*132 + col] = bfbits2f((unsigned int)kb[(size_t)row*HWN + n0 + col]);
      } else {
        int qr = row - 48;
        float v = (qr < 48) ? bfbits2f((unsigned int)qb[(size_t)qr*HWN + n0 + col])
                            : sb[(size_t)(qr - 48)*HWN + n0 + col];
        qcs[qr*132 + col] = v;
      }
    }
    __syncthreads();
    if (act) {
      for (int n = 0; n < 128; n += 4) {
        float4 kv0 = *(const float4*)&kcs[(d0+0)*132 + n];
        float4 kv1 = *(const float4*)&kcs[(d0+1)*132 + n];
        float4 kv2 = *(const float4*)&kcs[(d0+2)*132 + n];
        #pragma unroll
        for (int i = 0; i < 4; ++i) {
          if (c0 + i < C51) {
            float4 qv = *(const float4*)&qcs[(c0+i)*132 + n];
            acc[i][0] += qv.x*kv0.x + qv.y*kv0.y + qv.z*kv0.z + qv.w*kv0.w;
            acc[i][1] += qv.x*kv1.x + qv.y*kv1.y + qv.z*kv1.z + qv.w*kv1.w;
            acc[i][2] += qv.x*kv2.x + qv.y*kv2.y + qv.z*kv2.z + qv.w*kv2.w;
          }
        }
      }
    }
  }
  float* Gb = G + (size_t)(b*NH + h) * C51 * 48;
  if (act) {
    #pragma unroll
    for (int i = 0; i < 4; ++i) {
      if (c0 + i < C51) {
        #pragma unroll
        for (int j = 0; j < 3; ++j)
          atomicAdd(&Gb[(c0+i)*48 + d0 + j], acc[i][j]);
      }
    }
  }
}

// ---- K4: normalize+softmax -> attn; fold with proj_w -> W2[b,192,192] ------
__global__ __launch_bounds__(256) void k_attn_fold(
    const float* __restrict__ G, const float* __restrict__ ssq_qk,
    const float* __restrict__ ssq_svp, const float* __restrict__ temperature,
    const float* __restrict__ proj_w, float* __restrict__ W2)
{
  __shared__ float A[C51 * 48];
  __shared__ float qinv[C51];
  __shared__ float kinv[48];
  const int h = blockIdx.x, b = blockIdx.y;
  const int t = threadIdx.x;
  const float* Gb = G + (size_t)(b*NH + h) * C51 * 48;
  if (t < 48) kinv[t] = 1.f / fmaxf(sqrtf(ssq_qk[b*384 + 192 + h*48 + t]), 1e-12f);
  if (t >= 64 && t < 64 + C51) {
    int c = t - 64;
    float ss = (c < 48) ? ssq_qk[b*384 + h*48 + c] : ssq_svp[b*12 + h*3 + (c - 48)];
    qinv[c] = 1.f / fmaxf(sqrtf(ss), 1e-12f);
  }
  for (int idx = t; idx < C51*48; idx += 256) A[idx] = Gb[idx];
  __syncthreads();
  const float temp = temperature[h];
  if (t < C51) {
    float row[48];
    float m = -1e30f;
    const float qi = qinv[t] * temp;
    #pragma unroll
    for (int d = 0; d < 48; ++d) {
      float l = A[t*48 + d] * qi * kinv[d];
      row[d] = l; m = fmaxf(m, l);
    }
    float s = 0.f;
    #pragma unroll
    for (int d = 0; d < 48; ++d) { row[d] = expf(row[d] - m); s += row[d]; }
    const float inv = 1.f / s;
    #pragma unroll
    for (int d = 0; d < 48; ++d) A[t*48 + d] = row[d] * inv;
  }
  __syncthreads();
  for (int idx = t; idx < 192*48; idx += 256) {
    int o = idx / 48, d = idx - o*48;
    const float* pw = proj_w + o*204 + C51*h;
    float s = 0.f;
    #pragma unroll
    for (int c = 0; c < C51; ++c) s += pw[c] * A[c*48 + d];
    W2[((size_t)b*CCH + o)*CCH + h*48 + d] = s;
  }
}

// ---------- K5: out[b] = W2[b] (192x192, LDS) @ v (bf16) --------------------
__global__ __launch_bounds__(256) void k_out(
    const bf16* __restrict__ qkv, const float* __restrict__ W2,
    float* __restrict__ out)
{
  __shared__ float W2s[96 * 192];
  const int b = blockIdx.z, oh = blockIdx.y;
  const int n0 = blockIdx.x * 512;
  const int t = threadIdx.x;
  const float* wsrc = W2 + ((size_t)b*CCH + oh*96)*CCH;
  for (int idx = t; idx < 96*192/4; idx += 256)
    ((float4*)W2s)[idx] = ((const float4*)wsrc)[idx];
  __syncthreads();
  const unsigned short* vb = (const unsigned short*)qkv
        + ((size_t)b*OCN + 384)*HWN + n0 + 2*t;
  #pragma unroll 1
  for (int og = 0; og < 2; ++og) {
    float acc0[48], acc1[48];
    #pragma unroll
    for (int o = 0; o < 48; ++o) { acc0[o] = 0.f; acc1[o] = 0.f; }
    for (int j4 = 0; j4 < 192; j4 += 4) {
      float vx[4], vy[4];
      #pragma unroll
      for (int jj = 0; jj < 4; ++jj) {
        unsigned int u = *(const unsigned int*)(vb + (size_t)(j4 + jj)*HWN);
        vx[jj] = bfbits2f(u & 0xffffu);
        vy[jj] = bfbits2f(u >> 16);
      }
      const float* wrow = &W2s[og*48*192 + j4];
      #pragma unroll
      for (int o = 0; o < 48; ++o) {
        float4 w = *(const float4*)(wrow + o*192);
        acc0[o] += w.x*vx[0] + w.y*vx[1] + w.z*vx[2] + w.w*vx[3];
        acc1[o] += w.x*vy[0] + w.y*vy[1] + w.z*vy[2] + w.w*vy[3];
      }
    }
    float* ob = out + ((size_t)b*CCH + oh*96 + og*48)*HWN + n0 + 2*t;
    #pragma unroll
    for (int o = 0; o < 48; ++o) {
      float2 st = {acc0[o], acc1[o]};
      *(float2*)(ob + (size_t)o*HWN) = st;
    }
  }
}

// ---------------------------------------------------------------------------
extern "C" void kernel_launch(void* const* d_in, const int* in_sizes, int n_in,
                              void* d_out, int out_size, void* d_ws, size_t ws_size,
                              hipStream_t stream)
{
  const float* x       = (const float*)d_in[0];
  const float* svp_fea = (const float*)d_in[1];
  const float* qkv_w   = (const float*)d_in[2];
  const float* dw_w    = (const float*)d_in[3];
  const float* svp_w   = (const float*)d_in[4];
  const float* proj_w  = (const float*)d_in[5];
  const float* temp    = (const float*)d_in[6];
  float* outp = (float*)d_out;

  char* ws = (char*)d_ws;
  const size_t off_qkv1   = 0;                                      // 150,994,944
  const size_t off_qkv    = off_qkv1  + (size_t)BB*OCN*HWN*2;       // 150,994,944
  const size_t off_wb     = off_qkv   + (size_t)BB*OCN*HWN*2;       // 221,184
  const size_t off_svpq   = off_wb    + (size_t)OCN*CCH*2;          // 6,291,456
  const size_t off_ssqqk  = off_svpq  + (size_t)BB*12*HWN*4;
  const size_t off_ssqsvp = off_ssqqk + (size_t)BB*384*4;
  const size_t off_G      = off_ssqsvp+ (size_t)BB*12*4;
  const size_t off_W2     = off_G     + (size_t)BB*NH*C51*48*4;

  unsigned short* qkv1  = (unsigned short*)(ws + off_qkv1);
  bf16*  qkv     = (bf16*)(ws + off_qkv);
  unsigned short* xt    = (unsigned short*)(ws + off_qkv);  // aliases qkv: dead before k_dw writes
  unsigned short* wb    = (unsigned short*)(ws + off_wb);
  float* svp_q   = (float*)(ws + off_svpq);
  float* ssq_qk  = (float*)(ws + off_ssqqk);
  float* ssq_svp = (float*)(ws + off_ssqsvp);
  float* G       = (float*)(ws + off_G);
  float* W2      = (float*)(ws + off_W2);

  hipMemsetAsync(ws + off_ssqsvp, 0, (size_t)BB*12*4 + (size_t)BB*NH*C51*48*4, stream);

  k_castw    <<<dim3(108),        256, 0, stream>>>(qkv_w, wb);
  k_xt       <<<dim3(256, 6, BB), 256, 0, stream>>>(x, xt);
  k_svp      <<<dim3(64, BB),     256, 0, stream>>>(svp_fea, svp_w, svp_q, ssq_svp);
  k_gemm     <<<dim3(256, BB),    256, 0, stream>>>(xt, wb, qkv1);
  k_dw       <<<dim3(4, OCN, BB), 256, 0, stream>>>(qkv1, dw_w, (unsigned short*)qkv);
  k_norm     <<<dim3(384, BB),    256, 0, stream>>>(qkv, ssq_qk);
  k_gram     <<<dim3(16, NH, BB), 256, 0, stream>>>(qkv, svp_q, G);
  k_attn_fold<<<dim3(NH, BB),     256, 0, stream>>>(G, ssq_qk, ssq_svp, temp, proj_w, W2);
  k_out      <<<dim3(32, 2, BB),  256, 0, stream>>>(qkv, W2, outp);
}

// Round 3
// 649.721 us; speedup vs baseline: 5.5809x; 1.3859x over previous
//
#include <hip/hip_runtime.h>
#include <hip/hip_bf16.h>
#include <math.h>

#define BB   8
#define CCH  192
#define OCN  576
#define HWD  128
#define HWN  16384
#define NH   4
#define CHD  48
#define C51  51

typedef __hip_bfloat16 bf16;
typedef __attribute__((ext_vector_type(8))) short short8;
typedef __attribute__((ext_vector_type(4))) float f32x4;

__device__ __forceinline__ float bfbits2f(unsigned int u16) {
  union { unsigned int i; float f; } v; v.i = u16 << 16; return v.f;
}
__device__ __forceinline__ unsigned short f2bfbits(float f) {
  __hip_bfloat16 h = __float2bfloat16(f);
  return *(unsigned short*)&h;
}
__device__ __forceinline__ void stage16(const void* g, void* l) {
  __builtin_amdgcn_global_load_lds(
      (const __attribute__((address_space(1))) void*)g,
      (__attribute__((address_space(3))) void*)l, 16, 0, 0);
}

// ---------------- K0: svp 1x1 conv (3 -> 12) + sum-of-squares ----------------
__global__ __launch_bounds__(256) void k_svp(
    const float* __restrict__ svp_fea, const float* __restrict__ svp_w,
    float* __restrict__ svp_q, float* __restrict__ ssq_svp)
{
  const int b = blockIdx.y;
  const int n = blockIdx.x * 256 + threadIdx.x;
  const float* fb = svp_fea + (size_t)b * 3 * HWN;
  const float f0 = fb[n], f1 = fb[HWN + n], f2 = fb[2 * HWN + n];
  float* ob = svp_q + (size_t)b * 12 * HWN + n;
  #pragma unroll
  for (int r = 0; r < 12; ++r) {
    float o = svp_w[r*3]*f0 + svp_w[r*3+1]*f1 + svp_w[r*3+2]*f2;
    ob[(size_t)r * HWN] = o;
    float v = o * o;
    #pragma unroll
    for (int off = 32; off >= 1; off >>= 1) v += __shfl_down(v, off, 64);
    if ((threadIdx.x & 63) == 0) atomicAdd(&ssq_svp[b*12 + r], v);
  }
}

// ---------------- K0b: cast qkv_w (576x192 f32) -> bf16 ---------------------
__global__ __launch_bounds__(256) void k_castw(
    const float* __restrict__ w, unsigned short* __restrict__ wb)
{
  const int i = (blockIdx.x * 256 + threadIdx.x) * 4;
  float4 v = *(const float4*)(w + i);
  union { uint2 u; unsigned short s[4]; } pk;
  pk.s[0] = f2bfbits(v.x); pk.s[1] = f2bfbits(v.y);
  pk.s[2] = f2bfbits(v.z); pk.s[3] = f2bfbits(v.w);
  *(uint2*)(wb + i) = pk.u;
}

// ---------- K1: qkv1[b][576][HW] = W(bf16) @ x(f32->bf16), MFMA 16x16x32 ----
// X tile [64 n][192 c] reg-staged transposed from fp32 x, double-XOR swizzle.
// W tile via global_load_lds, single-XOR swizzle (both-sides rule 21).
__global__ __launch_bounds__(256) void k_gemm(
    const float* __restrict__ x, const unsigned short* __restrict__ wb,
    unsigned short* __restrict__ qkv1)
{
  __shared__ unsigned short Xs[64 * CCH];
  __shared__ unsigned short Ws[96 * CCH];
  const int b = blockIdx.y;
  const int n0 = blockIdx.x * 64;
  const int t = threadIdx.x;
  const int lane = t & 63, wave = t >> 6;
  const int wm = wave >> 1, wn = wave & 1;
  const int lq = lane >> 4, lr = lane & 15;

  const float* xb = x + (size_t)b * CCH * HWN + n0;
  #pragma unroll
  for (int rr = 0; rr < 12; ++rr) {
    int idx = rr * 256 + t;
    int c = idx >> 4, nq = idx & 15;
    float4 v = *(const float4*)(xb + (size_t)c * HWN + nq * 4);
    int g = c >> 3, co = c & 7;
    float vv[4] = {v.x, v.y, v.z, v.w};
    #pragma unroll
    for (int j = 0; j < 4; ++j) {
      int n = nq * 4 + j;
      int gs = (g & ~7) | ((g & 7) ^ (n & 7) ^ ((n >> 3) & 7));
      Xs[n * CCH + gs * 8 + co] = f2bfbits(vv[j]);
    }
  }

  for (int mc = 0; mc < 6; ++mc) {
    const unsigned short* wsrc = wb + (size_t)mc * 96 * CCH;
    #pragma unroll
    for (int i = 0; i < 9; ++i) {
      int chunk = wave * 9 + i;
      int d = chunk * 64 + lane;
      int row = d / 24, kg = d % 24;
      int skg = (kg & ~7) | ((kg & 7) ^ (row & 7));
      stage16(wsrc + (size_t)row * CCH + skg * 8, &Ws[0] + chunk * 512);
    }
    asm volatile("s_waitcnt vmcnt(0)" ::: "memory");
    __syncthreads();

    f32x4 acc[3][2];
    #pragma unroll
    for (int mf = 0; mf < 3; ++mf)
      #pragma unroll
      for (int nf = 0; nf < 2; ++nf) acc[mf][nf] = (f32x4)0.f;

    #pragma unroll
    for (int ks = 0; ks < 6; ++ks) {
      const int gk = ks * 4 + lq;
      short8 a[3], bb[2];
      #pragma unroll
      for (int mf = 0; mf < 3; ++mf) {
        int r = wm * 48 + mf * 16 + lr;
        int sg = (gk & ~7) | ((gk & 7) ^ (r & 7));
        a[mf] = *(const short8*)&Ws[r * CCH + sg * 8];
      }
      #pragma unroll
      for (int nf = 0; nf < 2; ++nf) {
        int r = wn * 32 + nf * 16 + lr;
        int sg = (gk & ~7) | ((gk & 7) ^ (r & 7) ^ ((r >> 3) & 7));
        bb[nf] = *(const short8*)&Xs[r * CCH + sg * 8];
      }
      #pragma unroll
      for (int mf = 0; mf < 3; ++mf)
        #pragma unroll
        for (int nf = 0; nf < 2; ++nf)
          acc[mf][nf] = __builtin_amdgcn_mfma_f32_16x16x32_bf16(
              a[mf], bb[nf], acc[mf][nf], 0, 0, 0);
    }

    unsigned short* ob = qkv1 + ((size_t)b * OCN + mc * 96 + wm * 48) * HWN
                         + n0 + wn * 32;
    #pragma unroll
    for (int mf = 0; mf < 3; ++mf)
      #pragma unroll
      for (int nf = 0; nf < 2; ++nf)
        #pragma unroll
        for (int r = 0; r < 4; ++r) {
          int m = mf * 16 + lq * 4 + r;
          int n = nf * 16 + lr;
          ob[(size_t)m * HWN + n] = f2bfbits(acc[mf][nf][r]);
        }
    __syncthreads();
  }
}

// ---------- K1b: depthwise 3x3 conv, bf16 -> bf16 (+ fused ssq for q,k) -----
__global__ __launch_bounds__(256) void k_dw(
    const unsigned short* __restrict__ qkv1, const float* __restrict__ dw_w,
    unsigned short* __restrict__ qkv, float* __restrict__ ssq_qk)
{
  __shared__ unsigned short ls[34][144];  // data cols 8..135, zero cols 7/136
  const int b = blockIdx.z, c = blockIdx.y, slab = blockIdx.x;
  const int r0 = slab * 32;
  const int t = threadIdx.x;
  const unsigned short* src = qkv1 + ((size_t)b * OCN + c) * HWN;
  for (int g = t; g < 544; g += 256) {
    int row = g >> 4, kc = g & 15;
    int grow = r0 + row - 1;
    uint4 v = make_uint4(0u, 0u, 0u, 0u);
    if ((unsigned)grow < 128u) v = *(const uint4*)(src + grow * HWD + kc * 8);
    *(uint4*)&ls[row][8 + kc * 8] = v;
  }
  if (t < 68) { int row = t >> 1; ls[row][7 + (t & 1) * 129] = 0; }
  __syncthreads();
  float w[9];
  #pragma unroll
  for (int i = 0; i < 9; ++i) w[i] = dw_w[c * 9 + i];
  const int cg = t & 15, rg = t >> 4;
  unsigned short* dst = qkv + ((size_t)b * OCN + c) * HWN;
  float ssq = 0.f;
  #pragma unroll
  for (int e = 0; e < 2; ++e) {
    int ro = rg * 2 + e;
    float acc[8];
    #pragma unroll
    for (int i = 0; i < 8; ++i) acc[i] = 0.f;
    #pragma unroll
    for (int j = 0; j < 3; ++j) {
      float v[10];
      #pragma unroll
      for (int i = 0; i < 10; ++i) v[i] = bfbits2f(ls[ro + j][7 + cg * 8 + i]);
      #pragma unroll
      for (int i = 0; i < 8; ++i)
        acc[i] += w[j*3]*v[i] + w[j*3+1]*v[i+1] + w[j*3+2]*v[i+2];
    }
    union { uint4 u; unsigned short s[8]; } pk;
    #pragma unroll
    for (int i = 0; i < 8; ++i) pk.s[i] = f2bfbits(acc[i]);
    *(uint4*)(dst + (size_t)(r0 + ro) * HWD + cg * 8) = pk.u;
    if (c < 384) {
      #pragma unroll
      for (int i = 0; i < 8; ++i) {
        float rv = bfbits2f(pk.s[i]);
        ssq += rv * rv;
      }
    }
  }
  if (c < 384) {
    #pragma unroll
    for (int off = 32; off >= 1; off >>= 1) ssq += __shfl_down(ssq, off, 64);
    if ((t & 63) == 0) atomicAdd(&ssq_qk[b * 384 + c], ssq);
  }
}

// ---------- K3: raw Gram G[b,h,51,48] = qcat @ k^T over HW (chunked) --------
__global__ __launch_bounds__(256) void k_gram(
    const bf16* __restrict__ qkv, const float* __restrict__ svp_q,
    float* __restrict__ G)
{
  __shared__ float kcs[48 * 132];
  __shared__ float qcs[C51 * 132];
  const int chunk = blockIdx.x, h = blockIdx.y, b = blockIdx.z;
  const int t = threadIdx.x;
  const int tq = t >> 4, td = t & 15;
  const int c0 = tq * 4, d0 = td * 3;
  const bool act = (tq < 13);
  float acc[4][3];
  #pragma unroll
  for (int i = 0; i < 4; ++i)
    #pragma unroll
    for (int j = 0; j < 3; ++j) acc[i][j] = 0.f;
  const unsigned short* qb = (const unsigned short*)qkv + ((size_t)b*OCN + h*CHD)*HWN;
  const unsigned short* kb = (const unsigned short*)qkv + ((size_t)b*OCN + 192 + h*CHD)*HWN;
  const float* sb = svp_q + ((size_t)b*12 + h*3)*HWN;
  for (int it = 0; it < 8; ++it) {
    const int n0 = chunk * 1024 + it * 128;
    __syncthreads();
    for (int idx = t; idx < 99 * 128; idx += 256) {
      int row = idx >> 7, col = idx & 127;
      if (row < 48) {
        kcs[row*132 + col] = bfbits2f((unsigned int)kb[(size_t)row*HWN + n0 + col]);
      } else {
        int qr = row - 48;
        float v = (qr < 48) ? bfbits2f((unsigned int)qb[(size_t)qr*HWN + n0 + col])
                            : sb[(size_t)(qr - 48)*HWN + n0 + col];
        qcs[qr*132 + col] = v;
      }
    }
    __syncthreads();
    if (act) {
      for (int n = 0; n < 128; n += 4) {
        float4 kv0 = *(const float4*)&kcs[(d0+0)*132 + n];
        float4 kv1 = *(const float4*)&kcs[(d0+1)*132 + n];
        float4 kv2 = *(const float4*)&kcs[(d0+2)*132 + n];
        #pragma unroll
        for (int i = 0; i < 4; ++i) {
          if (c0 + i < C51) {
            float4 qv = *(const float4*)&qcs[(c0+i)*132 + n];
            acc[i][0] += qv.x*kv0.x + qv.y*kv0.y + qv.z*kv0.z + qv.w*kv0.w;
            acc[i][1] += qv.x*kv1.x + qv.y*kv1.y + qv.z*kv1.z + qv.w*kv1.w;
            acc[i][2] += qv.x*kv2.x + qv.y*kv2.y + qv.z*kv2.z + qv.w*kv2.w;
          }
        }
      }
    }
  }
  float* Gb = G + (size_t)(b*NH + h) * C51 * 48;
  if (act) {
    #pragma unroll
    for (int i = 0; i < 4; ++i) {
      if (c0 + i < C51) {
        #pragma unroll
        for (int j = 0; j < 3; ++j)
          atomicAdd(&Gb[(c0+i)*48 + d0 + j], acc[i][j]);
      }
    }
  }
}

// ---- K4: normalize+softmax -> attn; fold with proj_w -> W2 (bf16) ----------
__global__ __launch_bounds__(256) void k_attn_fold(
    const float* __restrict__ G, const float* __restrict__ ssq_qk,
    const float* __restrict__ ssq_svp, const float* __restrict__ temperature,
    const float* __restrict__ proj_w, unsigned short* __restrict__ W2bf)
{
  __shared__ float A[C51 * 48];
  __shared__ float qinv[C51];
  __shared__ float kinv[48];
  const int h = blockIdx.x, b = blockIdx.y;
  const int t = threadIdx.x;
  const float* Gb = G + (size_t)(b*NH + h) * C51 * 48;
  if (t < 48) kinv[t] = 1.f / fmaxf(sqrtf(ssq_qk[b*384 + 192 + h*48 + t]), 1e-12f);
  if (t >= 64 && t < 64 + C51) {
    int c = t - 64;
    float ss = (c < 48) ? ssq_qk[b*384 + h*48 + c] : ssq_svp[b*12 + h*3 + (c - 48)];
    qinv[c] = 1.f / fmaxf(sqrtf(ss), 1e-12f);
  }
  for (int idx = t; idx < C51*48; idx += 256) A[idx] = Gb[idx];
  __syncthreads();
  const float temp = temperature[h];
  if (t < C51) {
    float row[48];
    float m = -1e30f;
    const float qi = qinv[t] * temp;
    #pragma unroll
    for (int d = 0; d < 48; ++d) {
      float l = A[t*48 + d] * qi * kinv[d];
      row[d] = l; m = fmaxf(m, l);
    }
    float s = 0.f;
    #pragma unroll
    for (int d = 0; d < 48; ++d) { row[d] = expf(row[d] - m); s += row[d]; }
    const float inv = 1.f / s;
    #pragma unroll
    for (int d = 0; d < 48; ++d) A[t*48 + d] = row[d] * inv;
  }
  __syncthreads();
  for (int idx = t; idx < 192*48; idx += 256) {
    int o = idx / 48, d = idx - o*48;
    const float* pw = proj_w + o*204 + C51*h;
    float s = 0.f;
    #pragma unroll
    for (int c = 0; c < C51; ++c) s += pw[c] * A[c*48 + d];
    W2bf[((size_t)b*CCH + o)*CCH + h*48 + d] = f2bfbits(s);
  }
}

// ---------- K5: out[b] = W2b(bf16) @ v(bf16) via MFMA, fp32 out -------------
__global__ __launch_bounds__(256) void k_out(
    const unsigned short* __restrict__ qkv, const unsigned short* __restrict__ w2b,
    float* __restrict__ out)
{
  __shared__ unsigned short Vs[64 * CCH];
  __shared__ unsigned short Ws[96 * CCH];
  const int b = blockIdx.y;
  const int n0 = blockIdx.x * 64;
  const int t = threadIdx.x;
  const int lane = t & 63, wave = t >> 6;
  const int wm = wave >> 1, wn = wave & 1;
  const int lq = lane >> 4, lr = lane & 15;

  const unsigned short* vb = qkv + ((size_t)b * OCN + 384) * HWN + n0;
  #pragma unroll
  for (int rr = 0; rr < 6; ++rr) {
    int idx = rr * 256 + t;
    int c = idx >> 3, nq = idx & 7;
    uint4 v = *(const uint4*)(vb + (size_t)c * HWN + nq * 8);
    union { uint4 u; unsigned short s[8]; } pk; pk.u = v;
    int g = c >> 3, co = c & 7;
    #pragma unroll
    for (int j = 0; j < 8; ++j) {
      int n = nq * 8 + j;
      int gs = (g & ~7) | ((g & 7) ^ (n & 7) ^ ((n >> 3) & 7));
      Vs[n * CCH + gs * 8 + co] = pk.s[j];
    }
  }

  for (int mc = 0; mc < 2; ++mc) {
    const unsigned short* wsrc = w2b + ((size_t)b * CCH + mc * 96) * CCH;
    #pragma unroll
    for (int i = 0; i < 9; ++i) {
      int chunk = wave * 9 + i;
      int d = chunk * 64 + lane;
      int row = d / 24, kg = d % 24;
      int skg = (kg & ~7) | ((kg & 7) ^ (row & 7));
      stage16(wsrc + (size_t)row * CCH + skg * 8, &Ws[0] + chunk * 512);
    }
    asm volatile("s_waitcnt vmcnt(0)" ::: "memory");
    __syncthreads();

    f32x4 acc[3][2];
    #pragma unroll
    for (int mf = 0; mf < 3; ++mf)
      #pragma unroll
      for (int nf = 0; nf < 2; ++nf) acc[mf][nf] = (f32x4)0.f;

    #pragma unroll
    for (int ks = 0; ks < 6; ++ks) {
      const int gk = ks * 4 + lq;
      short8 a[3], bb[2];
      #pragma unroll
      for (int mf = 0; mf < 3; ++mf) {
        int r = wm * 48 + mf * 16 + lr;
        int sg = (gk & ~7) | ((gk & 7) ^ (r & 7));
        a[mf] = *(const short8*)&Ws[r * CCH + sg * 8];
      }
      #pragma unroll
      for (int nf = 0; nf < 2; ++nf) {
        int r = wn * 32 + nf * 16 + lr;
        int sg = (gk & ~7) | ((gk & 7) ^ (r & 7) ^ ((r >> 3) & 7));
        bb[nf] = *(const short8*)&Vs[r * CCH + sg * 8];
      }
      #pragma unroll
      for (int mf = 0; mf < 3; ++mf)
        #pragma unroll
        for (int nf = 0; nf < 2; ++nf)
          acc[mf][nf] = __builtin_amdgcn_mfma_f32_16x16x32_bf16(
              a[mf], bb[nf], acc[mf][nf], 0, 0, 0);
    }

    float* ob = out + ((size_t)b * CCH + mc * 96 + wm * 48) * HWN + n0 + wn * 32;
    #pragma unroll
    for (int mf = 0; mf < 3; ++mf)
      #pragma unroll
      for (int nf = 0; nf < 2; ++nf)
        #pragma unroll
        for (int r = 0; r < 4; ++r) {
          int m = mf * 16 + lq * 4 + r;
          int n = nf * 16 + lr;
          ob[(size_t)m * HWN + n] = acc[mf][nf][r];
        }
    __syncthreads();
  }
}

// ---------------------------------------------------------------------------
extern "C" void kernel_launch(void* const* d_in, const int* in_sizes, int n_in,
                              void* d_out, int out_size, void* d_ws, size_t ws_size,
                              hipStream_t stream)
{
  const float* x       = (const float*)d_in[0];
  const float* svp_fea = (const float*)d_in[1];
  const float* qkv_w   = (const float*)d_in[2];
  const float* dw_w    = (const float*)d_in[3];
  const float* svp_w   = (const float*)d_in[4];
  const float* proj_w  = (const float*)d_in[5];
  const float* temp    = (const float*)d_in[6];
  float* outp = (float*)d_out;

  char* ws = (char*)d_ws;
  const size_t off_qkv1   = 0;
  const size_t off_qkv    = off_qkv1  + (size_t)BB*OCN*HWN*2;
  const size_t off_wb     = off_qkv   + (size_t)BB*OCN*HWN*2;
  const size_t off_svpq   = off_wb    + (size_t)OCN*CCH*2;
  const size_t off_ssqqk  = off_svpq  + (size_t)BB*12*HWN*4;
  const size_t off_ssqsvp = off_ssqqk + (size_t)BB*384*4;
  const size_t off_G      = off_ssqsvp+ (size_t)BB*12*4;
  const size_t off_W2     = off_G     + (size_t)BB*NH*C51*48*4;

  unsigned short* qkv1  = (unsigned short*)(ws + off_qkv1);
  bf16*  qkv     = (bf16*)(ws + off_qkv);
  unsigned short* wb    = (unsigned short*)(ws + off_wb);
  float* svp_q   = (float*)(ws + off_svpq);
  float* ssq_qk  = (float*)(ws + off_ssqqk);
  float* ssq_svp = (float*)(ws + off_ssqsvp);
  float* G       = (float*)(ws + off_G);
  unsigned short* W2bf  = (unsigned short*)(ws + off_W2);

  // zero ssq_qk + ssq_svp + G (contiguous)
  hipMemsetAsync(ws + off_ssqqk, 0,
                 (size_t)BB*384*4 + (size_t)BB*12*4 + (size_t)BB*NH*C51*48*4,
                 stream);

  k_castw    <<<dim3(108),        256, 0, stream>>>(qkv_w, wb);
  k_svp      <<<dim3(64, BB),     256, 0, stream>>>(svp_fea, svp_w, svp_q, ssq_svp);
  k_gemm     <<<dim3(256, BB),    256, 0, stream>>>(x, wb, qkv1);
  k_dw       <<<dim3(4, OCN, BB), 256, 0, stream>>>(qkv1, dw_w, (unsigned short*)qkv, ssq_qk);
  k_gram     <<<dim3(16, NH, BB), 256, 0, stream>>>(qkv, svp_q, G);
  k_attn_fold<<<dim3(NH, BB),     256, 0, stream>>>(G, ssq_qk, ssq_svp, temp, proj_w, W2bf);
  k_out      <<<dim3(256, BB),    256, 0, stream>>>((const unsigned short*)qkv, W2bf, outp);
}

// Round 5
// 425.805 us; speedup vs baseline: 8.5157x; 1.5259x over previous
//
#include <hip/hip_runtime.h>
#include <hip/hip_bf16.h>
#include <math.h>

#define BB   8
#define CCH  192
#define OCN  576
#define HWD  128
#define HWN  16384
#define NH   4
#define CHD  48
#define C51  51
#define GSZ  (C51*48)   // 2448 dense gram tile

typedef __hip_bfloat16 bf16;
typedef __attribute__((ext_vector_type(8))) short short8;
typedef __attribute__((ext_vector_type(4))) float f32x4;

__device__ __forceinline__ float bfbits2f(unsigned int u16) {
  union { unsigned int i; float f; } v; v.i = u16 << 16; return v.f;
}
__device__ __forceinline__ unsigned short f2bfbits(float f) {
  __hip_bfloat16 h = __float2bfloat16(f);
  return *(unsigned short*)&h;
}
__device__ __forceinline__ void stage16(const void* g, void* l) {
  __builtin_amdgcn_global_load_lds(
      (const __attribute__((address_space(1))) void*)g,
      (__attribute__((address_space(3))) void*)l, 16, 0, 0);
}

// ---------------- K0: svp 1x1 conv (3 -> 12) + sum-of-squares ----------------
__global__ __launch_bounds__(256) void k_svp(
    const float* __restrict__ svp_fea, const float* __restrict__ svp_w,
    float* __restrict__ svp_q, float* __restrict__ ssq_svp)
{
  const int b = blockIdx.y;
  const int n = blockIdx.x * 256 + threadIdx.x;
  const float* fb = svp_fea + (size_t)b * 3 * HWN;
  const float f0 = fb[n], f1 = fb[HWN + n], f2 = fb[2 * HWN + n];
  float* ob = svp_q + (size_t)b * 12 * HWN + n;
  #pragma unroll
  for (int r = 0; r < 12; ++r) {
    float o = svp_w[r*3]*f0 + svp_w[r*3+1]*f1 + svp_w[r*3+2]*f2;
    ob[(size_t)r * HWN] = o;
    float v = o * o;
    #pragma unroll
    for (int off = 32; off >= 1; off >>= 1) v += __shfl_down(v, off, 64);
    if ((threadIdx.x & 63) == 0) atomicAdd(&ssq_svp[b*12 + r], v);
  }
}

// ---------------- K0b: cast qkv_w (576x192 f32) -> bf16 ---------------------
__global__ __launch_bounds__(256) void k_castw(
    const float* __restrict__ w, unsigned short* __restrict__ wb)
{
  const int i = (blockIdx.x * 256 + threadIdx.x) * 4;
  float4 v = *(const float4*)(w + i);
  union { uint2 u; unsigned short s[4]; } pk;
  pk.s[0] = f2bfbits(v.x); pk.s[1] = f2bfbits(v.y);
  pk.s[2] = f2bfbits(v.z); pk.s[3] = f2bfbits(v.w);
  *(uint2*)(wb + i) = pk.u;
}

// ---------- K1: qkv1[b][576][HW] = W(bf16) @ x(f32->bf16), MFMA 16x16x32 ----
__global__ __launch_bounds__(256) void k_gemm(
    const float* __restrict__ x, const unsigned short* __restrict__ wb,
    unsigned short* __restrict__ qkv1)
{
  __shared__ unsigned short Xs[64 * CCH];
  __shared__ unsigned short Ws[96 * CCH];
  const int b = blockIdx.y;
  const int n0 = blockIdx.x * 64;
  const int t = threadIdx.x;
  const int lane = t & 63, wave = t >> 6;
  const int wm = wave >> 1, wn = wave & 1;
  const int lq = lane >> 4, lr = lane & 15;

  const float* xb = x + (size_t)b * CCH * HWN + n0;
  #pragma unroll
  for (int rr = 0; rr < 12; ++rr) {
    int idx = rr * 256 + t;
    int c = idx >> 4, nq = idx & 15;
    float4 v = *(const float4*)(xb + (size_t)c * HWN + nq * 4);
    int g = c >> 3, co = c & 7;
    float vv[4] = {v.x, v.y, v.z, v.w};
    #pragma unroll
    for (int j = 0; j < 4; ++j) {
      int n = nq * 4 + j;
      int gs = (g & ~7) | ((g & 7) ^ (n & 7) ^ ((n >> 3) & 7));
      Xs[n * CCH + gs * 8 + co] = f2bfbits(vv[j]);
    }
  }

  for (int mc = 0; mc < 6; ++mc) {
    const unsigned short* wsrc = wb + (size_t)mc * 96 * CCH;
    #pragma unroll
    for (int i = 0; i < 9; ++i) {
      int chunk = wave * 9 + i;
      int d = chunk * 64 + lane;
      int row = d / 24, kg = d % 24;
      int skg = (kg & ~7) | ((kg & 7) ^ (row & 7));
      stage16(wsrc + (size_t)row * CCH + skg * 8, &Ws[0] + chunk * 512);
    }
    asm volatile("s_waitcnt vmcnt(0)" ::: "memory");
    __syncthreads();

    f32x4 acc[3][2];
    #pragma unroll
    for (int mf = 0; mf < 3; ++mf)
      #pragma unroll
      for (int nf = 0; nf < 2; ++nf) acc[mf][nf] = (f32x4)0.f;

    #pragma unroll
    for (int ks = 0; ks < 6; ++ks) {
      const int gk = ks * 4 + lq;
      short8 a[3], bb[2];
      #pragma unroll
      for (int mf = 0; mf < 3; ++mf) {
        int r = wm * 48 + mf * 16 + lr;
        int sg = (gk & ~7) | ((gk & 7) ^ (r & 7));
        a[mf] = *(const short8*)&Ws[r * CCH + sg * 8];
      }
      #pragma unroll
      for (int nf = 0; nf < 2; ++nf) {
        int r = wn * 32 + nf * 16 + lr;
        int sg = (gk & ~7) | ((gk & 7) ^ (r & 7) ^ ((r >> 3) & 7));
        bb[nf] = *(const short8*)&Xs[r * CCH + sg * 8];
      }
      #pragma unroll
      for (int mf = 0; mf < 3; ++mf)
        #pragma unroll
        for (int nf = 0; nf < 2; ++nf)
          acc[mf][nf] = __builtin_amdgcn_mfma_f32_16x16x32_bf16(
              a[mf], bb[nf], acc[mf][nf], 0, 0, 0);
    }

    unsigned short* ob = qkv1 + ((size_t)b * OCN + mc * 96 + wm * 48) * HWN
                         + n0 + wn * 32;
    #pragma unroll
    for (int mf = 0; mf < 3; ++mf)
      #pragma unroll
      for (int nf = 0; nf < 2; ++nf)
        #pragma unroll
        for (int r = 0; r < 4; ++r) {
          int m = mf * 16 + lq * 4 + r;
          int n = nf * 16 + lr;
          ob[(size_t)m * HWN + n] = f2bfbits(acc[mf][nf][r]);
        }
    __syncthreads();
  }
}

// ---------- K1b: depthwise 3x3 conv, bf16 -> bf16 (+ fused ssq for q,k) -----
__global__ __launch_bounds__(256) void k_dw(
    const unsigned short* __restrict__ qkv1, const float* __restrict__ dw_w,
    unsigned short* __restrict__ qkv, float* __restrict__ ssq_qk)
{
  __shared__ unsigned short ls[34][144];  // data cols 8..135, zero cols 7/136
  const int b = blockIdx.z, c = blockIdx.y, slab = blockIdx.x;
  const int r0 = slab * 32;
  const int t = threadIdx.x;
  const unsigned short* src = qkv1 + ((size_t)b * OCN + c) * HWN;
  for (int g = t; g < 544; g += 256) {
    int row = g >> 4, kc = g & 15;
    int grow = r0 + row - 1;
    uint4 v = make_uint4(0u, 0u, 0u, 0u);
    if ((unsigned)grow < 128u) v = *(const uint4*)(src + grow * HWD + kc * 8);
    *(uint4*)&ls[row][8 + kc * 8] = v;
  }
  if (t < 68) { int row = t >> 1; ls[row][7 + (t & 1) * 129] = 0; }
  __syncthreads();
  float w[9];
  #pragma unroll
  for (int i = 0; i < 9; ++i) w[i] = dw_w[c * 9 + i];
  const int cg = t & 15, rg = t >> 4;
  unsigned short* dst = qkv + ((size_t)b * OCN + c) * HWN;
  float ssq = 0.f;
  #pragma unroll
  for (int e = 0; e < 2; ++e) {
    int ro = rg * 2 + e;
    float acc[8];
    #pragma unroll
    for (int i = 0; i < 8; ++i) acc[i] = 0.f;
    #pragma unroll
    for (int j = 0; j < 3; ++j) {
      float v[10];
      #pragma unroll
      for (int i = 0; i < 10; ++i) v[i] = bfbits2f(ls[ro + j][7 + cg * 8 + i]);
      #pragma unroll
      for (int i = 0; i < 8; ++i)
        acc[i] += w[j*3]*v[i] + w[j*3+1]*v[i+1] + w[j*3+2]*v[i+2];
    }
    union { uint4 u; unsigned short s[8]; } pk;
    #pragma unroll
    for (int i = 0; i < 8; ++i) pk.s[i] = f2bfbits(acc[i]);
    *(uint4*)(dst + (size_t)(r0 + ro) * HWD + cg * 8) = pk.u;
    if (c < 384) {
      #pragma unroll
      for (int i = 0; i < 8; ++i) {
        float rv = bfbits2f(pk.s[i]);
        ssq += rv * rv;
      }
    }
  }
  if (c < 384) {
    #pragma unroll
    for (int off = 32; off >= 1; off >>= 1) ssq += __shfl_down(ssq, off, 64);
    if ((t & 63) == 0) atomicAdd(&ssq_qk[b * 384 + c], ssq);
  }
}

// ---------- K3: Gram partials via MFMA, direct global loads -----------------
// grid (16 chunks, NH, BB), 4 waves; each wave: 256 spatial = 8 K-steps of 32.
// A = q channels (+1 frag for svp rows), B = k channels. Partial tile ->
// LDS reduce (4 deterministic passes) -> dense store to Gp[bh][chunk][2448].
__global__ __launch_bounds__(256) void k_gram(
    const unsigned short* __restrict__ qkv, const float* __restrict__ svp_q,
    float* __restrict__ Gp)
{
  __shared__ float Gs[C51 * 50];  // row stride 50: 2-way banks max
  const int chunk = blockIdx.x, h = blockIdx.y, b = blockIdx.z;
  const int t = threadIdx.x;
  const int lane = t & 63, wave = t >> 6;
  const int lq = lane >> 4, lr = lane & 15;
  const unsigned short* qb = qkv + ((size_t)b*OCN + h*CHD)*HWN;
  const unsigned short* kb = qkv + ((size_t)b*OCN + 192 + h*CHD)*HWN;
  const float* sb = svp_q + ((size_t)b*12 + h*3)*HWN;

  for (int idx = t; idx < C51*50; idx += 256) Gs[idx] = 0.f;

  f32x4 acc[3][3], sacc[3];
  #pragma unroll
  for (int mf = 0; mf < 3; ++mf)
    #pragma unroll
    for (int nf = 0; nf < 3; ++nf) acc[mf][nf] = (f32x4)0.f;
  #pragma unroll
  for (int nf = 0; nf < 3; ++nf) sacc[nf] = (f32x4)0.f;

  const int nbase = chunk * 1024 + wave * 256;
  #pragma unroll 4
  for (int ks = 0; ks < 8; ++ks) {
    const int n = nbase + ks * 32 + lq * 8;
    short8 a[3], bb[3];
    #pragma unroll
    for (int mf = 0; mf < 3; ++mf)
      a[mf] = *(const short8*)&qb[(size_t)(mf*16 + lr)*HWN + n];
    #pragma unroll
    for (int nf = 0; nf < 3; ++nf)
      bb[nf] = *(const short8*)&kb[(size_t)(nf*16 + lr)*HWN + n];
    union { short8 s8; unsigned short us[8]; } sv;
    #pragma unroll
    for (int i = 0; i < 8; ++i) sv.us[i] = 0;
    if (lr < 3) {
      const float* sp = sb + (size_t)lr*HWN + n;
      float4 v0 = *(const float4*)sp, v1 = *(const float4*)(sp + 4);
      sv.us[0] = f2bfbits(v0.x); sv.us[1] = f2bfbits(v0.y);
      sv.us[2] = f2bfbits(v0.z); sv.us[3] = f2bfbits(v0.w);
      sv.us[4] = f2bfbits(v1.x); sv.us[5] = f2bfbits(v1.y);
      sv.us[6] = f2bfbits(v1.z); sv.us[7] = f2bfbits(v1.w);
    }
    #pragma unroll
    for (int mf = 0; mf < 3; ++mf)
      #pragma unroll
      for (int nf = 0; nf < 3; ++nf)
        acc[mf][nf] = __builtin_amdgcn_mfma_f32_16x16x32_bf16(
            a[mf], bb[nf], acc[mf][nf], 0, 0, 0);
    #pragma unroll
    for (int nf = 0; nf < 3; ++nf)
      sacc[nf] = __builtin_amdgcn_mfma_f32_16x16x32_bf16(
          sv.s8, bb[nf], sacc[nf], 0, 0, 0);
  }

  __syncthreads();
  for (int w = 0; w < 4; ++w) {
    if (wave == w) {
      #pragma unroll
      for (int mf = 0; mf < 3; ++mf)
        #pragma unroll
        for (int nf = 0; nf < 3; ++nf)
          #pragma unroll
          for (int r = 0; r < 4; ++r)
            Gs[(mf*16 + lq*4 + r)*50 + nf*16 + lr] += acc[mf][nf][r];
      if (lq == 0) {
        #pragma unroll
        for (int nf = 0; nf < 3; ++nf)
          #pragma unroll
          for (int r = 0; r < 3; ++r)
            Gs[(48 + r)*50 + nf*16 + lr] += sacc[nf][r];
      }
    }
    __syncthreads();
  }
  float* Gout = Gp + ((size_t)((b*NH + h) * 16 + chunk)) * GSZ;
  for (int idx = t; idx < GSZ; idx += 256) {
    int row = idx / 48, col = idx - row * 48;
    Gout[idx] = Gs[row*50 + col];
  }
}

// ---- K4: reduce Gp; normalize+softmax; fold with proj_w -> W2 (bf16) -------
__global__ __launch_bounds__(256) void k_attn_fold(
    const float* __restrict__ Gp, const float* __restrict__ ssq_qk,
    const float* __restrict__ ssq_svp, const float* __restrict__ temperature,
    const float* __restrict__ proj_w, unsigned short* __restrict__ W2bf)
{
  __shared__ float A[GSZ];
  __shared__ float qinv[C51];
  __shared__ float kinv[48];
  const int h = blockIdx.x, b = blockIdx.y;
  const int t = threadIdx.x;
  const float* Gb = Gp + ((size_t)(b*NH + h) * 16) * GSZ;
  if (t < 48) kinv[t] = 1.f / fmaxf(sqrtf(ssq_qk[b*384 + 192 + h*48 + t]), 1e-12f);
  if (t >= 64 && t < 64 + C51) {
    int c = t - 64;
    float ss = (c < 48) ? ssq_qk[b*384 + h*48 + c] : ssq_svp[b*12 + h*3 + (c - 48)];
    qinv[c] = 1.f / fmaxf(sqrtf(ss), 1e-12f);
  }
  for (int idx = t; idx < GSZ; idx += 256) {
    float s = 0.f;
    #pragma unroll
    for (int c = 0; c < 16; ++c) s += Gb[(size_t)c * GSZ + idx];
    A[idx] = s;
  }
  __syncthreads();
  const float temp = temperature[h];
  if (t < C51) {
    float row[48];
    float m = -1e30f;
    const float qi = qinv[t] * temp;
    #pragma unroll
    for (int d = 0; d < 48; ++d) {
      float l = A[t*48 + d] * qi * kinv[d];
      row[d] = l; m = fmaxf(m, l);
    }
    float s = 0.f;
    #pragma unroll
    for (int d = 0; d < 48; ++d) { row[d] = expf(row[d] - m); s += row[d]; }
    const float inv = 1.f / s;
    #pragma unroll
    for (int d = 0; d < 48; ++d) A[t*48 + d] = row[d] * inv;
  }
  __syncthreads();
  for (int idx = t; idx < 192*48; idx += 256) {
    int o = idx / 48, d = idx - o*48;
    const float* pw = proj_w + o*204 + C51*h;
    float s = 0.f;
    #pragma unroll
    for (int c = 0; c < C51; ++c) s += pw[c] * A[c*48 + d];
    W2bf[((size_t)b*CCH + o)*CCH + h*48 + d] = f2bfbits(s);
  }
}

// ---------- K5: out[b] = W2b(bf16) @ v(bf16) via MFMA, fp32 out -------------
__global__ __launch_bounds__(256) void k_out(
    const unsigned short* __restrict__ qkv, const unsigned short* __restrict__ w2b,
    float* __restrict__ out)
{
  __shared__ unsigned short Vs[64 * CCH];
  __shared__ unsigned short Ws[96 * CCH];
  const int b = blockIdx.y;
  const int n0 = blockIdx.x * 64;
  const int t = threadIdx.x;
  const int lane = t & 63, wave = t >> 6;
  const int wm = wave >> 1, wn = wave & 1;
  const int lq = lane >> 4, lr = lane & 15;

  const unsigned short* vb = qkv + ((size_t)b * OCN + 384) * HWN + n0;
  #pragma unroll
  for (int rr = 0; rr < 6; ++rr) {
    int idx = rr * 256 + t;
    int c = idx >> 3, nq = idx & 7;
    uint4 v = *(const uint4*)(vb + (size_t)c * HWN + nq * 8);
    union { uint4 u; unsigned short s[8]; } pk; pk.u = v;
    int g = c >> 3, co = c & 7;
    #pragma unroll
    for (int j = 0; j < 8; ++j) {
      int n = nq * 8 + j;
      int gs = (g & ~7) | ((g & 7) ^ (n & 7) ^ ((n >> 3) & 7));
      Vs[n * CCH + gs * 8 + co] = pk.s[j];
    }
  }

  for (int mc = 0; mc < 2; ++mc) {
    const unsigned short* wsrc = w2b + ((size_t)b * CCH + mc * 96) * CCH;
    #pragma unroll
    for (int i = 0; i < 9; ++i) {
      int chunk = wave * 9 + i;
      int d = chunk * 64 + lane;
      int row = d / 24, kg = d % 24;
      int skg = (kg & ~7) | ((kg & 7) ^ (row & 7));
      stage16(wsrc + (size_t)row * CCH + skg * 8, &Ws[0] + chunk * 512);
    }
    asm volatile("s_waitcnt vmcnt(0)" ::: "memory");
    __syncthreads();

    f32x4 acc[3][2];
    #pragma unroll
    for (int mf = 0; mf < 3; ++mf)
      #pragma unroll
      for (int nf = 0; nf < 2; ++nf) acc[mf][nf] = (f32x4)0.f;

    #pragma unroll
    for (int ks = 0; ks < 6; ++ks) {
      const int gk = ks * 4 + lq;
      short8 a[3], bb[2];
      #pragma unroll
      for (int mf = 0; mf < 3; ++mf) {
        int r = wm * 48 + mf * 16 + lr;
        int sg = (gk & ~7) | ((gk & 7) ^ (r & 7));
        a[mf] = *(const short8*)&Ws[r * CCH + sg * 8];
      }
      #pragma unroll
      for (int nf = 0; nf < 2; ++nf) {
        int r = wn * 32 + nf * 16 + lr;
        int sg = (gk & ~7) | ((gk & 7) ^ (r & 7) ^ ((r >> 3) & 7));
        bb[nf] = *(const short8*)&Vs[r * CCH + sg * 8];
      }
      #pragma unroll
      for (int mf = 0; mf < 3; ++mf)
        #pragma unroll
        for (int nf = 0; nf < 2; ++nf)
          acc[mf][nf] = __builtin_amdgcn_mfma_f32_16x16x32_bf16(
              a[mf], bb[nf], acc[mf][nf], 0, 0, 0);
    }

    float* ob = out + ((size_t)b * CCH + mc * 96 + wm * 48) * HWN + n0 + wn * 32;
    #pragma unroll
    for (int mf = 0; mf < 3; ++mf)
      #pragma unroll
      for (int nf = 0; nf < 2; ++nf)
        #pragma unroll
        for (int r = 0; r < 4; ++r) {
          int m = mf * 16 + lq * 4 + r;
          int n = nf * 16 + lr;
          ob[(size_t)m * HWN + n] = acc[mf][nf][r];
        }
    __syncthreads();
  }
}

// ---------------------------------------------------------------------------
extern "C" void kernel_launch(void* const* d_in, const int* in_sizes, int n_in,
                              void* d_out, int out_size, void* d_ws, size_t ws_size,
                              hipStream_t stream)
{
  const float* x       = (const float*)d_in[0];
  const float* svp_fea = (const float*)d_in[1];
  const float* qkv_w   = (const float*)d_in[2];
  const float* dw_w    = (const float*)d_in[3];
  const float* svp_w   = (const float*)d_in[4];
  const float* proj_w  = (const float*)d_in[5];
  const float* temp    = (const float*)d_in[6];
  float* outp = (float*)d_out;

  char* ws = (char*)d_ws;
  const size_t off_qkv1   = 0;
  const size_t off_qkv    = off_qkv1  + (size_t)BB*OCN*HWN*2;
  const size_t off_wb     = off_qkv   + (size_t)BB*OCN*HWN*2;
  const size_t off_svpq   = off_wb    + (size_t)OCN*CCH*2;
  const size_t off_ssqqk  = off_svpq  + (size_t)BB*12*HWN*4;
  const size_t off_ssqsvp = off_ssqqk + (size_t)BB*384*4;
  const size_t off_Gp     = off_ssqsvp+ (size_t)BB*12*4;
  const size_t off_W2     = off_Gp    + (size_t)BB*NH*16*GSZ*4;  // 5.0 MB

  unsigned short* qkv1  = (unsigned short*)(ws + off_qkv1);
  bf16*  qkv     = (bf16*)(ws + off_qkv);
  unsigned short* wb    = (unsigned short*)(ws + off_wb);
  float* svp_q   = (float*)(ws + off_svpq);
  float* ssq_qk  = (float*)(ws + off_ssqqk);
  float* ssq_svp = (float*)(ws + off_ssqsvp);
  float* Gp      = (float*)(ws + off_Gp);
  unsigned short* W2bf  = (unsigned short*)(ws + off_W2);

  // zero ssq_qk + ssq_svp (contiguous); Gp uses plain stores
  hipMemsetAsync(ws + off_ssqqk, 0, (size_t)BB*384*4 + (size_t)BB*12*4, stream);

  k_castw    <<<dim3(108),         256, 0, stream>>>(qkv_w, wb);
  k_svp      <<<dim3(64, BB),      256, 0, stream>>>(svp_fea, svp_w, svp_q, ssq_svp);
  k_gemm     <<<dim3(256, BB),     256, 0, stream>>>(x, wb, qkv1);
  k_dw       <<<dim3(4, OCN, BB),  256, 0, stream>>>(qkv1, dw_w, (unsigned short*)qkv, ssq_qk);
  k_gram     <<<dim3(16, NH, BB),  256, 0, stream>>>((const unsigned short*)qkv, svp_q, Gp);
  k_attn_fold<<<dim3(NH, BB),      256, 0, stream>>>(Gp, ssq_qk, ssq_svp, temp, proj_w, W2bf);
  k_out      <<<dim3(256, BB),     256, 0, stream>>>((const unsigned short*)qkv, W2bf, outp);
}

// Round 6
// 417.426 us; speedup vs baseline: 8.6866x; 1.0201x over previous
//
#include <hip/hip_runtime.h>
#include <hip/hip_bf16.h>
#include <math.h>

#define BB   8
#define CCH  192
#define OCN  576
#define HWD  128
#define HWN  16384
#define NH   4
#define CHD  48
#define C51  51
#define GSZ  (C51*48)   // 2448 dense gram tile

typedef __hip_bfloat16 bf16;
typedef __attribute__((ext_vector_type(8))) short short8;
typedef __attribute__((ext_vector_type(4))) float f32x4;

__device__ __forceinline__ float bfbits2f(unsigned int u16) {
  union { unsigned int i; float f; } v; v.i = u16 << 16; return v.f;
}
__device__ __forceinline__ unsigned short f2bfbits(float f) {
  __hip_bfloat16 h = __float2bfloat16(f);
  return *(unsigned short*)&h;
}
__device__ __forceinline__ void stage16(const void* g, void* l) {
  __builtin_amdgcn_global_load_lds(
      (const __attribute__((address_space(1))) void*)g,
      (__attribute__((address_space(3))) void*)l, 16, 0, 0);
}

// ---------------- K0: svp 1x1 conv (3 -> 12) + sum-of-squares ----------------
__global__ __launch_bounds__(256) void k_svp(
    const float* __restrict__ svp_fea, const float* __restrict__ svp_w,
    float* __restrict__ svp_q, float* __restrict__ ssq_svp)
{
  const int b = blockIdx.y;
  const int n = blockIdx.x * 256 + threadIdx.x;
  const float* fb = svp_fea + (size_t)b * 3 * HWN;
  const float f0 = fb[n], f1 = fb[HWN + n], f2 = fb[2 * HWN + n];
  float* ob = svp_q + (size_t)b * 12 * HWN + n;
  #pragma unroll
  for (int r = 0; r < 12; ++r) {
    float o = svp_w[r*3]*f0 + svp_w[r*3+1]*f1 + svp_w[r*3+2]*f2;
    ob[(size_t)r * HWN] = o;
    float v = o * o;
    #pragma unroll
    for (int off = 32; off >= 1; off >>= 1) v += __shfl_down(v, off, 64);
    if ((threadIdx.x & 63) == 0) atomicAdd(&ssq_svp[b*12 + r], v);
  }
}

// ---------------- K0b: cast qkv_w (576x192 f32) -> bf16 ---------------------
__global__ __launch_bounds__(256) void k_castw(
    const float* __restrict__ w, unsigned short* __restrict__ wb)
{
  const int i = (blockIdx.x * 256 + threadIdx.x) * 4;
  float4 v = *(const float4*)(w + i);
  union { uint2 u; unsigned short s[4]; } pk;
  pk.s[0] = f2bfbits(v.x); pk.s[1] = f2bfbits(v.y);
  pk.s[2] = f2bfbits(v.z); pk.s[3] = f2bfbits(v.w);
  *(uint2*)(wb + i) = pk.u;
}

// ---------- K1: qkv1[b][576][HW] = W(bf16) @ x(f32->bf16), MFMA 16x16x32 ----
__global__ __launch_bounds__(256) void k_gemm(
    const float* __restrict__ x, const unsigned short* __restrict__ wb,
    unsigned short* __restrict__ qkv1)
{
  __shared__ unsigned short Xs[64 * CCH];
  __shared__ unsigned short Ws[96 * CCH];
  const int b = blockIdx.y;
  const int n0 = blockIdx.x * 64;
  const int t = threadIdx.x;
  const int lane = t & 63, wave = t >> 6;
  const int wm = wave >> 1, wn = wave & 1;
  const int lq = lane >> 4, lr = lane & 15;

  const float* xb = x + (size_t)b * CCH * HWN + n0;
  #pragma unroll
  for (int rr = 0; rr < 12; ++rr) {
    int idx = rr * 256 + t;
    int c = idx >> 4, nq = idx & 15;
    float4 v = *(const float4*)(xb + (size_t)c * HWN + nq * 4);
    int g = c >> 3, co = c & 7;
    float vv[4] = {v.x, v.y, v.z, v.w};
    #pragma unroll
    for (int j = 0; j < 4; ++j) {
      int n = nq * 4 + j;
      int gs = (g & ~7) | ((g & 7) ^ (n & 7) ^ ((n >> 3) & 7));
      Xs[n * CCH + gs * 8 + co] = f2bfbits(vv[j]);
    }
  }

  for (int mc = 0; mc < 6; ++mc) {
    const unsigned short* wsrc = wb + (size_t)mc * 96 * CCH;
    #pragma unroll
    for (int i = 0; i < 9; ++i) {
      int chunk = wave * 9 + i;
      int d = chunk * 64 + lane;
      int row = d / 24, kg = d % 24;
      int skg = (kg & ~7) | ((kg & 7) ^ (row & 7));
      stage16(wsrc + (size_t)row * CCH + skg * 8, &Ws[0] + chunk * 512);
    }
    asm volatile("s_waitcnt vmcnt(0)" ::: "memory");
    __syncthreads();

    f32x4 acc[3][2];
    #pragma unroll
    for (int mf = 0; mf < 3; ++mf)
      #pragma unroll
      for (int nf = 0; nf < 2; ++nf) acc[mf][nf] = (f32x4)0.f;

    #pragma unroll
    for (int ks = 0; ks < 6; ++ks) {
      const int gk = ks * 4 + lq;
      short8 a[3], bb[2];
      #pragma unroll
      for (int mf = 0; mf < 3; ++mf) {
        int r = wm * 48 + mf * 16 + lr;
        int sg = (gk & ~7) | ((gk & 7) ^ (r & 7));
        a[mf] = *(const short8*)&Ws[r * CCH + sg * 8];
      }
      #pragma unroll
      for (int nf = 0; nf < 2; ++nf) {
        int r = wn * 32 + nf * 16 + lr;
        int sg = (gk & ~7) | ((gk & 7) ^ (r & 7) ^ ((r >> 3) & 7));
        bb[nf] = *(const short8*)&Xs[r * CCH + sg * 8];
      }
      #pragma unroll
      for (int mf = 0; mf < 3; ++mf)
        #pragma unroll
        for (int nf = 0; nf < 2; ++nf)
          acc[mf][nf] = __builtin_amdgcn_mfma_f32_16x16x32_bf16(
              a[mf], bb[nf], acc[mf][nf], 0, 0, 0);
    }

    unsigned short* ob = qkv1 + ((size_t)b * OCN + mc * 96 + wm * 48) * HWN
                         + n0 + wn * 32;
    #pragma unroll
    for (int mf = 0; mf < 3; ++mf)
      #pragma unroll
      for (int nf = 0; nf < 2; ++nf)
        #pragma unroll
        for (int r = 0; r < 4; ++r) {
          int m = mf * 16 + lq * 4 + r;
          int n = nf * 16 + lr;
          ob[(size_t)m * HWN + n] = f2bfbits(acc[mf][nf][r]);
        }
    __syncthreads();
  }
}

// ---------- K1b: depthwise 3x3 conv, fp32 LDS + ds_read_b128 ----------------
// ls[34][136]: global row (r0+row-1) at ls[row], data col x at ls[.][4+x];
// cols 0..3 / 132..135 zeroed -> halo handled without branches in compute.
__global__ __launch_bounds__(256) void k_dw(
    const unsigned short* __restrict__ qkv1, const float* __restrict__ dw_w,
    unsigned short* __restrict__ qkv, float* __restrict__ ssq_qk)
{
  __shared__ float ls[34][136];
  const int b = blockIdx.z, c = blockIdx.y, slab = blockIdx.x;
  const int r0 = slab * 32;
  const int t = threadIdx.x;
  const unsigned short* src = qkv1 + ((size_t)b * OCN + c) * HWN;
  for (int g = t; g < 544; g += 256) {
    int row = g >> 4, kc = g & 15;
    int grow = r0 + row - 1;
    uint4 v = make_uint4(0u, 0u, 0u, 0u);
    if ((unsigned)grow < 128u) v = *(const uint4*)(src + grow * HWD + kc * 8);
    unsigned int ua[4] = {v.x, v.y, v.z, v.w};
    float4 f0, f1;
    f0.x = bfbits2f(ua[0] & 0xffffu); f0.y = bfbits2f(ua[0] >> 16);
    f0.z = bfbits2f(ua[1] & 0xffffu); f0.w = bfbits2f(ua[1] >> 16);
    f1.x = bfbits2f(ua[2] & 0xffffu); f1.y = bfbits2f(ua[2] >> 16);
    f1.z = bfbits2f(ua[3] & 0xffffu); f1.w = bfbits2f(ua[3] >> 16);
    *(float4*)&ls[row][4 + kc * 8] = f0;
    *(float4*)&ls[row][8 + kc * 8] = f1;
  }
  if (t < 68) {
    int row = t >> 1;
    int base = (t & 1) ? 132 : 0;
    ls[row][base + 0] = 0.f; ls[row][base + 1] = 0.f;
    ls[row][base + 2] = 0.f; ls[row][base + 3] = 0.f;
  }
  __syncthreads();
  float w[9];
  #pragma unroll
  for (int i = 0; i < 9; ++i) w[i] = dw_w[c * 9 + i];
  const int cg = t & 15, rg = t >> 4;
  // register buffer: 4 input rows x 16 cols (ls cols 8cg .. 8cg+15)
  float rbuf[4][16];
  #pragma unroll
  for (int j = 0; j < 4; ++j)
    #pragma unroll
    for (int q = 0; q < 4; ++q)
      *(float4*)&rbuf[j][q * 4] = *(const float4*)&ls[2 * rg + j][8 * cg + q * 4];

  unsigned short* dst = qkv + ((size_t)b * OCN + c) * HWN;
  float ssq = 0.f;
  #pragma unroll
  for (int e = 0; e < 2; ++e) {
    float acc[8];
    #pragma unroll
    for (int i = 0; i < 8; ++i) acc[i] = 0.f;
    #pragma unroll
    for (int j = 0; j < 3; ++j) {
      const float* vr = rbuf[e + j];
      #pragma unroll
      for (int i = 0; i < 8; ++i)
        acc[i] += w[j*3]*vr[i+3] + w[j*3+1]*vr[i+4] + w[j*3+2]*vr[i+5];
    }
    union { uint4 u; unsigned short s[8]; } pk;
    #pragma unroll
    for (int i = 0; i < 8; ++i) pk.s[i] = f2bfbits(acc[i]);
    *(uint4*)(dst + (size_t)(r0 + 2*rg + e) * HWD + cg * 8) = pk.u;
    if (c < 384) {
      #pragma unroll
      for (int i = 0; i < 8; ++i) {
        float rv = bfbits2f(pk.s[i]);
        ssq += rv * rv;
      }
    }
  }
  if (c < 384) {
    #pragma unroll
    for (int off = 32; off >= 1; off >>= 1) ssq += __shfl_down(ssq, off, 64);
    if ((t & 63) == 0) atomicAdd(&ssq_qk[b * 384 + c], ssq);
  }
}

// ---------- K3: Gram partials via MFMA, direct global loads -----------------
__global__ __launch_bounds__(256) void k_gram(
    const unsigned short* __restrict__ qkv, const float* __restrict__ svp_q,
    float* __restrict__ Gp)
{
  __shared__ float Gs[C51 * 50];  // row stride 50: 2-way banks max
  const int chunk = blockIdx.x, h = blockIdx.y, b = blockIdx.z;
  const int t = threadIdx.x;
  const int lane = t & 63, wave = t >> 6;
  const int lq = lane >> 4, lr = lane & 15;
  const unsigned short* qb = qkv + ((size_t)b*OCN + h*CHD)*HWN;
  const unsigned short* kb = qkv + ((size_t)b*OCN + 192 + h*CHD)*HWN;
  const float* sb = svp_q + ((size_t)b*12 + h*3)*HWN;

  for (int idx = t; idx < C51*50; idx += 256) Gs[idx] = 0.f;

  f32x4 acc[3][3], sacc[3];
  #pragma unroll
  for (int mf = 0; mf < 3; ++mf)
    #pragma unroll
    for (int nf = 0; nf < 3; ++nf) acc[mf][nf] = (f32x4)0.f;
  #pragma unroll
  for (int nf = 0; nf < 3; ++nf) sacc[nf] = (f32x4)0.f;

  const int nbase = chunk * 1024 + wave * 256;
  #pragma unroll 4
  for (int ks = 0; ks < 8; ++ks) {
    const int n = nbase + ks * 32 + lq * 8;
    short8 a[3], bb[3];
    #pragma unroll
    for (int mf = 0; mf < 3; ++mf)
      a[mf] = *(const short8*)&qb[(size_t)(mf*16 + lr)*HWN + n];
    #pragma unroll
    for (int nf = 0; nf < 3; ++nf)
      bb[nf] = *(const short8*)&kb[(size_t)(nf*16 + lr)*HWN + n];
    union { short8 s8; unsigned short us[8]; } sv;
    #pragma unroll
    for (int i = 0; i < 8; ++i) sv.us[i] = 0;
    if (lr < 3) {
      const float* sp = sb + (size_t)lr*HWN + n;
      float4 v0 = *(const float4*)sp, v1 = *(const float4*)(sp + 4);
      sv.us[0] = f2bfbits(v0.x); sv.us[1] = f2bfbits(v0.y);
      sv.us[2] = f2bfbits(v0.z); sv.us[3] = f2bfbits(v0.w);
      sv.us[4] = f2bfbits(v1.x); sv.us[5] = f2bfbits(v1.y);
      sv.us[6] = f2bfbits(v1.z); sv.us[7] = f2bfbits(v1.w);
    }
    #pragma unroll
    for (int mf = 0; mf < 3; ++mf)
      #pragma unroll
      for (int nf = 0; nf < 3; ++nf)
        acc[mf][nf] = __builtin_amdgcn_mfma_f32_16x16x32_bf16(
            a[mf], bb[nf], acc[mf][nf], 0, 0, 0);
    #pragma unroll
    for (int nf = 0; nf < 3; ++nf)
      sacc[nf] = __builtin_amdgcn_mfma_f32_16x16x32_bf16(
          sv.s8, bb[nf], sacc[nf], 0, 0, 0);
  }

  __syncthreads();
  for (int w = 0; w < 4; ++w) {
    if (wave == w) {
      #pragma unroll
      for (int mf = 0; mf < 3; ++mf)
        #pragma unroll
        for (int nf = 0; nf < 3; ++nf)
          #pragma unroll
          for (int r = 0; r < 4; ++r)
            Gs[(mf*16 + lq*4 + r)*50 + nf*16 + lr] += acc[mf][nf][r];
      if (lq == 0) {
        #pragma unroll
        for (int nf = 0; nf < 3; ++nf)
          #pragma unroll
          for (int r = 0; r < 3; ++r)
            Gs[(48 + r)*50 + nf*16 + lr] += sacc[nf][r];
      }
    }
    __syncthreads();
  }
  float* Gout = Gp + ((size_t)((b*NH + h) * 16 + chunk)) * GSZ;
  for (int idx = t; idx < GSZ; idx += 256) {
    int row = idx / 48, col = idx - row * 48;
    Gout[idx] = Gs[row*50 + col];
  }
}

// ---- K4: reduce Gp; normalize+softmax; fold with proj_w -> W2 (bf16) -------
__global__ __launch_bounds__(256) void k_attn_fold(
    const float* __restrict__ Gp, const float* __restrict__ ssq_qk,
    const float* __restrict__ ssq_svp, const float* __restrict__ temperature,
    const float* __restrict__ proj_w, unsigned short* __restrict__ W2bf)
{
  __shared__ float A[GSZ];
  __shared__ float qinv[C51];
  __shared__ float kinv[48];
  const int h = blockIdx.x, b = blockIdx.y;
  const int t = threadIdx.x;
  const float* Gb = Gp + ((size_t)(b*NH + h) * 16) * GSZ;
  if (t < 48) kinv[t] = 1.f / fmaxf(sqrtf(ssq_qk[b*384 + 192 + h*48 + t]), 1e-12f);
  if (t >= 64 && t < 64 + C51) {
    int c = t - 64;
    float ss = (c < 48) ? ssq_qk[b*384 + h*48 + c] : ssq_svp[b*12 + h*3 + (c - 48)];
    qinv[c] = 1.f / fmaxf(sqrtf(ss), 1e-12f);
  }
  for (int idx = t; idx < GSZ; idx += 256) {
    float s = 0.f;
    #pragma unroll
    for (int c = 0; c < 16; ++c) s += Gb[(size_t)c * GSZ + idx];
    A[idx] = s;
  }
  __syncthreads();
  const float temp = temperature[h];
  if (t < C51) {
    float row[48];
    float m = -1e30f;
    const float qi = qinv[t] * temp;
    #pragma unroll
    for (int d = 0; d < 48; ++d) {
      float l = A[t*48 + d] * qi * kinv[d];
      row[d] = l; m = fmaxf(m, l);
    }
    float s = 0.f;
    #pragma unroll
    for (int d = 0; d < 48; ++d) { row[d] = expf(row[d] - m); s += row[d]; }
    const float inv = 1.f / s;
    #pragma unroll
    for (int d = 0; d < 48; ++d) A[t*48 + d] = row[d] * inv;
  }
  __syncthreads();
  for (int idx = t; idx < 192*48; idx += 256) {
    int o = idx / 48, d = idx - o*48;
    const float* pw = proj_w + o*204 + C51*h;
    float s = 0.f;
    #pragma unroll
    for (int c = 0; c < C51; ++c) s += pw[c] * A[c*48 + d];
    W2bf[((size_t)b*CCH + o)*CCH + h*48 + d] = f2bfbits(s);
  }
}

// ---------- K5: out[b] = W2b(bf16) @ v(bf16) via MFMA, fp32 out -------------
__global__ __launch_bounds__(256) void k_out(
    const unsigned short* __restrict__ qkv, const unsigned short* __restrict__ w2b,
    float* __restrict__ out)
{
  __shared__ unsigned short Vs[64 * CCH];
  __shared__ unsigned short Ws[96 * CCH];
  const int b = blockIdx.y;
  const int n0 = blockIdx.x * 64;
  const int t = threadIdx.x;
  const int lane = t & 63, wave = t >> 6;
  const int wm = wave >> 1, wn = wave & 1;
  const int lq = lane >> 4, lr = lane & 15;

  const unsigned short* vb = qkv + ((size_t)b * OCN + 384) * HWN + n0;
  #pragma unroll
  for (int rr = 0; rr < 6; ++rr) {
    int idx = rr * 256 + t;
    int c = idx >> 3, nq = idx & 7;
    uint4 v = *(const uint4*)(vb + (size_t)c * HWN + nq * 8);
    union { uint4 u; unsigned short s[8]; } pk; pk.u = v;
    int g = c >> 3, co = c & 7;
    #pragma unroll
    for (int j = 0; j < 8; ++j) {
      int n = nq * 8 + j;
      int gs = (g & ~7) | ((g & 7) ^ (n & 7) ^ ((n >> 3) & 7));
      Vs[n * CCH + gs * 8 + co] = pk.s[j];
    }
  }

  for (int mc = 0; mc < 2; ++mc) {
    const unsigned short* wsrc = w2b + ((size_t)b * CCH + mc * 96) * CCH;
    #pragma unroll
    for (int i = 0; i < 9; ++i) {
      int chunk = wave * 9 + i;
      int d = chunk * 64 + lane;
      int row = d / 24, kg = d % 24;
      int skg = (kg & ~7) | ((kg & 7) ^ (row & 7));
      stage16(wsrc + (size_t)row * CCH + skg * 8, &Ws[0] + chunk * 512);
    }
    asm volatile("s_waitcnt vmcnt(0)" ::: "memory");
    __syncthreads();

    f32x4 acc[3][2];
    #pragma unroll
    for (int mf = 0; mf < 3; ++mf)
      #pragma unroll
      for (int nf = 0; nf < 2; ++nf) acc[mf][nf] = (f32x4)0.f;

    #pragma unroll
    for (int ks = 0; ks < 6; ++ks) {
      const int gk = ks * 4 + lq;
      short8 a[3], bb[2];
      #pragma unroll
      for (int mf = 0; mf < 3; ++mf) {
        int r = wm * 48 + mf * 16 + lr;
        int sg = (gk & ~7) | ((gk & 7) ^ (r & 7));
        a[mf] = *(const short8*)&Ws[r * CCH + sg * 8];
      }
      #pragma unroll
      for (int nf = 0; nf < 2; ++nf) {
        int r = wn * 32 + nf * 16 + lr;
        int sg = (gk & ~7) | ((gk & 7) ^ (r & 7) ^ ((r >> 3) & 7));
        bb[nf] = *(const short8*)&Vs[r * CCH + sg * 8];
      }
      #pragma unroll
      for (int mf = 0; mf < 3; ++mf)
        #pragma unroll
        for (int nf = 0; nf < 2; ++nf)
          acc[mf][nf] = __builtin_amdgcn_mfma_f32_16x16x32_bf16(
              a[mf], bb[nf], acc[mf][nf], 0, 0, 0);
    }

    float* ob = out + ((size_t)b * CCH + mc * 96 + wm * 48) * HWN + n0 + wn * 32;
    #pragma unroll
    for (int mf = 0; mf < 3; ++mf)
      #pragma unroll
      for (int nf = 0; nf < 2; ++nf)
        #pragma unroll
        for (int r = 0; r < 4; ++r) {
          int m = mf * 16 + lq * 4 + r;
          int n = nf * 16 + lr;
          ob[(size_t)m * HWN + n] = acc[mf][nf][r];
        }
    __syncthreads();
  }
}

// ---------------------------------------------------------------------------
extern "C" void kernel_launch(void* const* d_in, const int* in_sizes, int n_in,
                              void* d_out, int out_size, void* d_ws, size_t ws_size,
                              hipStream_t stream)
{
  const float* x       = (const float*)d_in[0];
  const float* svp_fea = (const float*)d_in[1];
  const float* qkv_w   = (const float*)d_in[2];
  const float* dw_w    = (const float*)d_in[3];
  const float* svp_w   = (const float*)d_in[4];
  const float* proj_w  = (const float*)d_in[5];
  const float* temp    = (const float*)d_in[6];
  float* outp = (float*)d_out;

  char* ws = (char*)d_ws;
  const size_t off_qkv1   = 0;
  const size_t off_qkv    = off_qkv1  + (size_t)BB*OCN*HWN*2;
  const size_t off_wb     = off_qkv   + (size_t)BB*OCN*HWN*2;
  const size_t off_svpq   = off_wb    + (size_t)OCN*CCH*2;
  const size_t off_ssqqk  = off_svpq  + (size_t)BB*12*HWN*4;
  const size_t off_ssqsvp = off_ssqqk + (size_t)BB*384*4;
  const size_t off_Gp     = off_ssqsvp+ (size_t)BB*12*4;
  const size_t off_W2     = off_Gp    + (size_t)BB*NH*16*GSZ*4;  // 5.0 MB

  unsigned short* qkv1  = (unsigned short*)(ws + off_qkv1);
  bf16*  qkv     = (bf16*)(ws + off_qkv);
  unsigned short* wb    = (unsigned short*)(ws + off_wb);
  float* svp_q   = (float*)(ws + off_svpq);
  float* ssq_qk  = (float*)(ws + off_ssqqk);
  float* ssq_svp = (float*)(ws + off_ssqsvp);
  float* Gp      = (float*)(ws + off_Gp);
  unsigned short* W2bf  = (unsigned short*)(ws + off_W2);

  // zero ssq_qk + ssq_svp (contiguous); Gp uses plain stores
  hipMemsetAsync(ws + off_ssqqk, 0, (size_t)BB*384*4 + (size_t)BB*12*4, stream);

  k_castw    <<<dim3(108),         256, 0, stream>>>(qkv_w, wb);
  k_svp      <<<dim3(64, BB),      256, 0, stream>>>(svp_fea, svp_w, svp_q, ssq_svp);
  k_gemm     <<<dim3(256, BB),     256, 0, stream>>>(x, wb, qkv1);
  k_dw       <<<dim3(4, OCN, BB),  256, 0, stream>>>(qkv1, dw_w, (unsigned short*)qkv, ssq_qk);
  k_gram     <<<dim3(16, NH, BB),  256, 0, stream>>>((const unsigned short*)qkv, svp_q, Gp);
  k_attn_fold<<<dim3(NH, BB),      256, 0, stream>>>(Gp, ssq_qk, ssq_svp, temp, proj_w, W2bf);
  k_out      <<<dim3(256, BB),     256, 0, stream>>>((const unsigned short*)qkv, W2bf, outp);
}

// Round 7
// 390.834 us; speedup vs baseline: 9.2777x; 1.0680x over previous
//
#include <hip/hip_runtime.h>
#include <hip/hip_bf16.h>
#include <math.h>

#define BB   8
#define CCH  192
#define OCN  576
#define HWD  128
#define HWN  16384
#define NH   4
#define CHD  48
#define C51  51
#define GSZ  (C51*48)   // 2448 dense gram tile

typedef __hip_bfloat16 bf16;
typedef __attribute__((ext_vector_type(8))) short short8;
typedef __attribute__((ext_vector_type(4))) float f32x4;

__device__ __forceinline__ float bfbits2f(unsigned int u16) {
  union { unsigned int i; float f; } v; v.i = u16 << 16; return v.f;
}
__device__ __forceinline__ unsigned short f2bfbits(float f) {
  __hip_bfloat16 h = __float2bfloat16(f);
  return *(unsigned short*)&h;
}
__device__ __forceinline__ void stage16(const void* g, void* l) {
  __builtin_amdgcn_global_load_lds(
      (const __attribute__((address_space(1))) void*)g,
      (__attribute__((address_space(3))) void*)l, 16, 0, 0);
}

// ---------------- K0: svp 1x1 conv (3 -> 12) + sum-of-squares ----------------
__global__ __launch_bounds__(256) void k_svp(
    const float* __restrict__ svp_fea, const float* __restrict__ svp_w,
    float* __restrict__ svp_q, float* __restrict__ ssq_svp)
{
  const int b = blockIdx.y;
  const int n = blockIdx.x * 256 + threadIdx.x;
  const float* fb = svp_fea + (size_t)b * 3 * HWN;
  const float f0 = fb[n], f1 = fb[HWN + n], f2 = fb[2 * HWN + n];
  float* ob = svp_q + (size_t)b * 12 * HWN + n;
  #pragma unroll
  for (int r = 0; r < 12; ++r) {
    float o = svp_w[r*3]*f0 + svp_w[r*3+1]*f1 + svp_w[r*3+2]*f2;
    ob[(size_t)r * HWN] = o;
    float v = o * o;
    #pragma unroll
    for (int off = 32; off >= 1; off >>= 1) v += __shfl_down(v, off, 64);
    if ((threadIdx.x & 63) == 0) atomicAdd(&ssq_svp[b*12 + r], v);
  }
}

// ---------------- K0b: cast qkv_w (576x192 f32) -> bf16 ---------------------
__global__ __launch_bounds__(256) void k_castw(
    const float* __restrict__ w, unsigned short* __restrict__ wb)
{
  const int i = (blockIdx.x * 256 + threadIdx.x) * 4;
  float4 v = *(const float4*)(w + i);
  union { uint2 u; unsigned short s[4]; } pk;
  pk.s[0] = f2bfbits(v.x); pk.s[1] = f2bfbits(v.y);
  pk.s[2] = f2bfbits(v.z); pk.s[3] = f2bfbits(v.w);
  *(uint2*)(wb + i) = pk.u;
}

// ---------- K1: qkv1[b][576][HW] = W(bf16) @ x(f32->bf16), MFMA 16x16x32 ----
// X staged by channel-pairs: 2 float4 loads -> 4 packed ds_write_b32.
__global__ __launch_bounds__(256) void k_gemm(
    const float* __restrict__ x, const unsigned short* __restrict__ wb,
    unsigned short* __restrict__ qkv1)
{
  __shared__ unsigned short Xs[64 * CCH];
  __shared__ unsigned short Ws[96 * CCH];
  const int b = blockIdx.y;
  const int n0 = blockIdx.x * 64;
  const int t = threadIdx.x;
  const int lane = t & 63, wave = t >> 6;
  const int wm = wave >> 1, wn = wave & 1;
  const int lq = lane >> 4, lr = lane & 15;

  const float* xb = x + (size_t)b * CCH * HWN + n0;
  #pragma unroll
  for (int rr = 0; rr < 6; ++rr) {
    int idx = rr * 256 + t;
    int cp = idx >> 4, nq = idx & 15;
    int c0 = cp * 2;
    float4 v0 = *(const float4*)(xb + (size_t)c0 * HWN + nq * 4);
    float4 v1 = *(const float4*)(xb + (size_t)(c0 + 1) * HWN + nq * 4);
    int g = c0 >> 3, co = c0 & 7;
    float a0[4] = {v0.x, v0.y, v0.z, v0.w};
    float a1[4] = {v1.x, v1.y, v1.z, v1.w};
    #pragma unroll
    for (int j = 0; j < 4; ++j) {
      int n = nq * 4 + j;
      int gs = (g & ~7) | ((g & 7) ^ (n & 7) ^ ((n >> 3) & 7));
      unsigned int pk = (unsigned int)f2bfbits(a0[j])
                      | ((unsigned int)f2bfbits(a1[j]) << 16);
      *(unsigned int*)&Xs[n * CCH + gs * 8 + co] = pk;
    }
  }

  for (int mc = 0; mc < 6; ++mc) {
    const unsigned short* wsrc = wb + (size_t)mc * 96 * CCH;
    #pragma unroll
    for (int i = 0; i < 9; ++i) {
      int chunk = wave * 9 + i;
      int d = chunk * 64 + lane;
      int row = d / 24, kg = d % 24;
      int skg = (kg & ~7) | ((kg & 7) ^ (row & 7));
      stage16(wsrc + (size_t)row * CCH + skg * 8, &Ws[0] + chunk * 512);
    }
    asm volatile("s_waitcnt vmcnt(0)" ::: "memory");
    __syncthreads();

    f32x4 acc[3][2];
    #pragma unroll
    for (int mf = 0; mf < 3; ++mf)
      #pragma unroll
      for (int nf = 0; nf < 2; ++nf) acc[mf][nf] = (f32x4)0.f;

    #pragma unroll
    for (int ks = 0; ks < 6; ++ks) {
      const int gk = ks * 4 + lq;
      short8 a[3], bb[2];
      #pragma unroll
      for (int mf = 0; mf < 3; ++mf) {
        int r = wm * 48 + mf * 16 + lr;
        int sg = (gk & ~7) | ((gk & 7) ^ (r & 7));
        a[mf] = *(const short8*)&Ws[r * CCH + sg * 8];
      }
      #pragma unroll
      for (int nf = 0; nf < 2; ++nf) {
        int r = wn * 32 + nf * 16 + lr;
        int sg = (gk & ~7) | ((gk & 7) ^ (r & 7) ^ ((r >> 3) & 7));
        bb[nf] = *(const short8*)&Xs[r * CCH + sg * 8];
      }
      #pragma unroll
      for (int mf = 0; mf < 3; ++mf)
        #pragma unroll
        for (int nf = 0; nf < 2; ++nf)
          acc[mf][nf] = __builtin_amdgcn_mfma_f32_16x16x32_bf16(
              a[mf], bb[nf], acc[mf][nf], 0, 0, 0);
    }

    unsigned short* ob = qkv1 + ((size_t)b * OCN + mc * 96 + wm * 48) * HWN
                         + n0 + wn * 32;
    #pragma unroll
    for (int mf = 0; mf < 3; ++mf)
      #pragma unroll
      for (int nf = 0; nf < 2; ++nf)
        #pragma unroll
        for (int r = 0; r < 4; ++r) {
          int m = mf * 16 + lq * 4 + r;
          int n = nf * 16 + lr;
          ob[(size_t)m * HWN + n] = f2bfbits(acc[mf][nf][r]);
        }
    __syncthreads();
  }
}

// ---------- K1b: depthwise 3x3 conv, LDS-free streaming ---------------------
// thread: 2 output rows x 8 cols; loads 4 input rows x 10 cols directly from
// global (uint4 + dword + u16, all aligned); overlap absorbed by L1/L2.
__global__ __launch_bounds__(256) void k_dw(
    const unsigned short* __restrict__ qkv1, const float* __restrict__ dw_w,
    unsigned short* __restrict__ qkv, float* __restrict__ ssq_qk)
{
  const int b = blockIdx.z, c = blockIdx.y, slab = blockIdx.x;
  const int t = threadIdx.x;
  const int cg = t & 15, rg = t >> 4;
  const int y0 = slab * 32 + rg * 2;   // first output row
  const unsigned short* src = qkv1 + ((size_t)b * OCN + c) * HWN;
  float w[9];
  #pragma unroll
  for (int i = 0; i < 9; ++i) w[i] = dw_w[c * 9 + i];

  float rows[4][10];
  #pragma unroll
  for (int j = 0; j < 4; ++j) {
    int gr = y0 - 1 + j;
    uint4 B = make_uint4(0u, 0u, 0u, 0u);
    unsigned int Al = 0; unsigned int Cv = 0;
    if ((unsigned)gr < 128u) {
      const unsigned short* rp = src + (size_t)gr * HWD;
      B = *(const uint4*)(rp + cg * 8);
      if (cg > 0)  Al = *(const unsigned int*)(rp + cg * 8 - 2);
      if (cg < 15) Cv = (unsigned int)rp[cg * 8 + 8];
    }
    rows[j][0] = bfbits2f(Al >> 16);
    unsigned int ub[4] = {B.x, B.y, B.z, B.w};
    #pragma unroll
    for (int q = 0; q < 4; ++q) {
      rows[j][1 + 2*q] = bfbits2f(ub[q] & 0xffffu);
      rows[j][2 + 2*q] = bfbits2f(ub[q] >> 16);
    }
    rows[j][9] = bfbits2f(Cv);
  }

  unsigned short* dst = qkv + ((size_t)b * OCN + c) * HWN;
  float ssq = 0.f;
  #pragma unroll
  for (int e = 0; e < 2; ++e) {
    float acc[8];
    #pragma unroll
    for (int i = 0; i < 8; ++i) acc[i] = 0.f;
    #pragma unroll
    for (int j = 0; j < 3; ++j) {
      const float* vr = rows[e + j];
      #pragma unroll
      for (int i = 0; i < 8; ++i)
        acc[i] += w[j*3]*vr[i] + w[j*3+1]*vr[i+1] + w[j*3+2]*vr[i+2];
    }
    union { uint4 u; unsigned short s[8]; } pk;
    #pragma unroll
    for (int i = 0; i < 8; ++i) pk.s[i] = f2bfbits(acc[i]);
    *(uint4*)(dst + (size_t)(y0 + e) * HWD + cg * 8) = pk.u;
    if (c < 384) {
      #pragma unroll
      for (int i = 0; i < 8; ++i) {
        float rv = bfbits2f(pk.s[i]);
        ssq += rv * rv;
      }
    }
  }
  if (c < 384) {
    #pragma unroll
    for (int off = 32; off >= 1; off >>= 1) ssq += __shfl_down(ssq, off, 64);
    if ((t & 63) == 0) atomicAdd(&ssq_qk[b * 384 + c], ssq);
  }
}

// ---------- K3: Gram partials via MFMA, direct global loads -----------------
__global__ __launch_bounds__(256) void k_gram(
    const unsigned short* __restrict__ qkv, const float* __restrict__ svp_q,
    float* __restrict__ Gp)
{
  __shared__ float Gs[C51 * 50];  // row stride 50: 2-way banks max
  const int chunk = blockIdx.x, h = blockIdx.y, b = blockIdx.z;
  const int t = threadIdx.x;
  const int lane = t & 63, wave = t >> 6;
  const int lq = lane >> 4, lr = lane & 15;
  const unsigned short* qb = qkv + ((size_t)b*OCN + h*CHD)*HWN;
  const unsigned short* kb = qkv + ((size_t)b*OCN + 192 + h*CHD)*HWN;
  const float* sb = svp_q + ((size_t)b*12 + h*3)*HWN;

  for (int idx = t; idx < C51*50; idx += 256) Gs[idx] = 0.f;

  f32x4 acc[3][3], sacc[3];
  #pragma unroll
  for (int mf = 0; mf < 3; ++mf)
    #pragma unroll
    for (int nf = 0; nf < 3; ++nf) acc[mf][nf] = (f32x4)0.f;
  #pragma unroll
  for (int nf = 0; nf < 3; ++nf) sacc[nf] = (f32x4)0.f;

  const int nbase = chunk * 1024 + wave * 256;
  #pragma unroll 4
  for (int ks = 0; ks < 8; ++ks) {
    const int n = nbase + ks * 32 + lq * 8;
    short8 a[3], bb[3];
    #pragma unroll
    for (int mf = 0; mf < 3; ++mf)
      a[mf] = *(const short8*)&qb[(size_t)(mf*16 + lr)*HWN + n];
    #pragma unroll
    for (int nf = 0; nf < 3; ++nf)
      bb[nf] = *(const short8*)&kb[(size_t)(nf*16 + lr)*HWN + n];
    union { short8 s8; unsigned short us[8]; } sv;
    #pragma unroll
    for (int i = 0; i < 8; ++i) sv.us[i] = 0;
    if (lr < 3) {
      const float* sp = sb + (size_t)lr*HWN + n;
      float4 v0 = *(const float4*)sp, v1 = *(const float4*)(sp + 4);
      sv.us[0] = f2bfbits(v0.x); sv.us[1] = f2bfbits(v0.y);
      sv.us[2] = f2bfbits(v0.z); sv.us[3] = f2bfbits(v0.w);
      sv.us[4] = f2bfbits(v1.x); sv.us[5] = f2bfbits(v1.y);
      sv.us[6] = f2bfbits(v1.z); sv.us[7] = f2bfbits(v1.w);
    }
    #pragma unroll
    for (int mf = 0; mf < 3; ++mf)
      #pragma unroll
      for (int nf = 0; nf < 3; ++nf)
        acc[mf][nf] = __builtin_amdgcn_mfma_f32_16x16x32_bf16(
            a[mf], bb[nf], acc[mf][nf], 0, 0, 0);
    #pragma unroll
    for (int nf = 0; nf < 3; ++nf)
      sacc[nf] = __builtin_amdgcn_mfma_f32_16x16x32_bf16(
          sv.s8, bb[nf], sacc[nf], 0, 0, 0);
  }

  __syncthreads();
  for (int w = 0; w < 4; ++w) {
    if (wave == w) {
      #pragma unroll
      for (int mf = 0; mf < 3; ++mf)
        #pragma unroll
        for (int nf = 0; nf < 3; ++nf)
          #pragma unroll
          for (int r = 0; r < 4; ++r)
            Gs[(mf*16 + lq*4 + r)*50 + nf*16 + lr] += acc[mf][nf][r];
      if (lq == 0) {
        #pragma unroll
        for (int nf = 0; nf < 3; ++nf)
          #pragma unroll
          for (int r = 0; r < 3; ++r)
            Gs[(48 + r)*50 + nf*16 + lr] += sacc[nf][r];
      }
    }
    __syncthreads();
  }
  float* Gout = Gp + ((size_t)((b*NH + h) * 16 + chunk)) * GSZ;
  for (int idx = t; idx < GSZ; idx += 256) {
    int row = idx / 48, col = idx - row * 48;
    Gout[idx] = Gs[row*50 + col];
  }
}

// ---- K4: reduce Gp; normalize+softmax; fold with proj_w -> W2 (bf16) -------
__global__ __launch_bounds__(256) void k_attn_fold(
    const float* __restrict__ Gp, const float* __restrict__ ssq_qk,
    const float* __restrict__ ssq_svp, const float* __restrict__ temperature,
    const float* __restrict__ proj_w, unsigned short* __restrict__ W2bf)
{
  __shared__ float A[GSZ];
  __shared__ float qinv[C51];
  __shared__ float kinv[48];
  const int h = blockIdx.x, b = blockIdx.y;
  const int t = threadIdx.x;
  const float* Gb = Gp + ((size_t)(b*NH + h) * 16) * GSZ;
  if (t < 48) kinv[t] = 1.f / fmaxf(sqrtf(ssq_qk[b*384 + 192 + h*48 + t]), 1e-12f);
  if (t >= 64 && t < 64 + C51) {
    int c = t - 64;
    float ss = (c < 48) ? ssq_qk[b*384 + h*48 + c] : ssq_svp[b*12 + h*3 + (c - 48)];
    qinv[c] = 1.f / fmaxf(sqrtf(ss), 1e-12f);
  }
  for (int idx = t; idx < GSZ; idx += 256) {
    float s = 0.f;
    #pragma unroll
    for (int c = 0; c < 16; ++c) s += Gb[(size_t)c * GSZ + idx];
    A[idx] = s;
  }
  __syncthreads();
  const float temp = temperature[h];
  if (t < C51) {
    float row[48];
    float m = -1e30f;
    const float qi = qinv[t] * temp;
    #pragma unroll
    for (int d = 0; d < 48; ++d) {
      float l = A[t*48 + d] * qi * kinv[d];
      row[d] = l; m = fmaxf(m, l);
    }
    float s = 0.f;
    #pragma unroll
    for (int d = 0; d < 48; ++d) { row[d] = expf(row[d] - m); s += row[d]; }
    const float inv = 1.f / s;
    #pragma unroll
    for (int d = 0; d < 48; ++d) A[t*48 + d] = row[d] * inv;
  }
  __syncthreads();
  for (int idx = t; idx < 192*48; idx += 256) {
    int o = idx / 48, d = idx - o*48;
    const float* pw = proj_w + o*204 + C51*h;
    float s = 0.f;
    #pragma unroll
    for (int c = 0; c < C51; ++c) s += pw[c] * A[c*48 + d];
    W2bf[((size_t)b*CCH + o)*CCH + h*48 + d] = f2bfbits(s);
  }
}

// ---------- K5: out[b] = W2b(bf16) @ v(bf16) via MFMA, fp32 out -------------
__global__ __launch_bounds__(256) void k_out(
    const unsigned short* __restrict__ qkv, const unsigned short* __restrict__ w2b,
    float* __restrict__ out)
{
  __shared__ unsigned short Vs[64 * CCH];
  __shared__ unsigned short Ws[96 * CCH];
  const int b = blockIdx.y;
  const int n0 = blockIdx.x * 64;
  const int t = threadIdx.x;
  const int lane = t & 63, wave = t >> 6;
  const int wm = wave >> 1, wn = wave & 1;
  const int lq = lane >> 4, lr = lane & 15;

  const unsigned short* vb = qkv + ((size_t)b * OCN + 384) * HWN + n0;
  #pragma unroll
  for (int rr = 0; rr < 3; ++rr) {
    int idx = rr * 256 + t;
    int cp = idx >> 3, nq = idx & 7;
    int c0 = cp * 2;
    uint4 v0 = *(const uint4*)(vb + (size_t)c0 * HWN + nq * 8);
    uint4 v1 = *(const uint4*)(vb + (size_t)(c0 + 1) * HWN + nq * 8);
    union { uint4 u; unsigned short s[8]; } p0, p1;
    p0.u = v0; p1.u = v1;
    int g = c0 >> 3, co = c0 & 7;
    #pragma unroll
    for (int j = 0; j < 8; ++j) {
      int n = nq * 8 + j;
      int gs = (g & ~7) | ((g & 7) ^ (n & 7) ^ ((n >> 3) & 7));
      unsigned int pk = (unsigned int)p0.s[j] | ((unsigned int)p1.s[j] << 16);
      *(unsigned int*)&Vs[n * CCH + gs * 8 + co] = pk;
    }
  }

  for (int mc = 0; mc < 2; ++mc) {
    const unsigned short* wsrc = w2b + ((size_t)b * CCH + mc * 96) * CCH;
    #pragma unroll
    for (int i = 0; i < 9; ++i) {
      int chunk = wave * 9 + i;
      int d = chunk * 64 + lane;
      int row = d / 24, kg = d % 24;
      int skg = (kg & ~7) | ((kg & 7) ^ (row & 7));
      stage16(wsrc + (size_t)row * CCH + skg * 8, &Ws[0] + chunk * 512);
    }
    asm volatile("s_waitcnt vmcnt(0)" ::: "memory");
    __syncthreads();

    f32x4 acc[3][2];
    #pragma unroll
    for (int mf = 0; mf < 3; ++mf)
      #pragma unroll
      for (int nf = 0; nf < 2; ++nf) acc[mf][nf] = (f32x4)0.f;

    #pragma unroll
    for (int ks = 0; ks < 6; ++ks) {
      const int gk = ks * 4 + lq;
      short8 a[3], bb[2];
      #pragma unroll
      for (int mf = 0; mf < 3; ++mf) {
        int r = wm * 48 + mf * 16 + lr;
        int sg = (gk & ~7) | ((gk & 7) ^ (r & 7));
        a[mf] = *(const short8*)&Ws[r * CCH + sg * 8];
      }
      #pragma unroll
      for (int nf = 0; nf < 2; ++nf) {
        int r = wn * 32 + nf * 16 + lr;
        int sg = (gk & ~7) | ((gk & 7) ^ (r & 7) ^ ((r >> 3) & 7));
        bb[nf] = *(const short8*)&Vs[r * CCH + sg * 8];
      }
      #pragma unroll
      for (int mf = 0; mf < 3; ++mf)
        #pragma unroll
        for (int nf = 0; nf < 2; ++nf)
          acc[mf][nf] = __builtin_amdgcn_mfma_f32_16x16x32_bf16(
              a[mf], bb[nf], acc[mf][nf], 0, 0, 0);
    }

    float* ob = out + ((size_t)b * CCH + mc * 96 + wm * 48) * HWN + n0 + wn * 32;
    #pragma unroll
    for (int mf = 0; mf < 3; ++mf)
      #pragma unroll
      for (int nf = 0; nf < 2; ++nf)
        #pragma unroll
        for (int r = 0; r < 4; ++r) {
          int m = mf * 16 + lq * 4 + r;
          int n = nf * 16 + lr;
          ob[(size_t)m * HWN + n] = acc[mf][nf][r];
        }
    __syncthreads();
  }
}

// ---------------------------------------------------------------------------
extern "C" void kernel_launch(void* const* d_in, const int* in_sizes, int n_in,
                              void* d_out, int out_size, void* d_ws, size_t ws_size,
                              hipStream_t stream)
{
  const float* x       = (const float*)d_in[0];
  const float* svp_fea = (const float*)d_in[1];
  const float* qkv_w   = (const float*)d_in[2];
  const float* dw_w    = (const float*)d_in[3];
  const float* svp_w   = (const float*)d_in[4];
  const float* proj_w  = (const float*)d_in[5];
  const float* temp    = (const float*)d_in[6];
  float* outp = (float*)d_out;

  char* ws = (char*)d_ws;
  const size_t off_qkv1   = 0;
  const size_t off_qkv    = off_qkv1  + (size_t)BB*OCN*HWN*2;
  const size_t off_wb     = off_qkv   + (size_t)BB*OCN*HWN*2;
  const size_t off_svpq   = off_wb    + (size_t)OCN*CCH*2;
  const size_t off_ssqqk  = off_svpq  + (size_t)BB*12*HWN*4;
  const size_t off_ssqsvp = off_ssqqk + (size_t)BB*384*4;
  const size_t off_Gp     = off_ssqsvp+ (size_t)BB*12*4;
  const size_t off_W2     = off_Gp    + (size_t)BB*NH*16*GSZ*4;  // 5.0 MB

  unsigned short* qkv1  = (unsigned short*)(ws + off_qkv1);
  bf16*  qkv     = (bf16*)(ws + off_qkv);
  unsigned short* wb    = (unsigned short*)(ws + off_wb);
  float* svp_q   = (float*)(ws + off_svpq);
  float* ssq_qk  = (float*)(ws + off_ssqqk);
  float* ssq_svp = (float*)(ws + off_ssqsvp);
  float* Gp      = (float*)(ws + off_Gp);
  unsigned short* W2bf  = (unsigned short*)(ws + off_W2);

  // zero ssq_qk + ssq_svp (contiguous); Gp uses plain stores
  hipMemsetAsync(ws + off_ssqqk, 0, (size_t)BB*384*4 + (size_t)BB*12*4, stream);

  k_castw    <<<dim3(108),         256, 0, stream>>>(qkv_w, wb);
  k_svp      <<<dim3(64, BB),      256, 0, stream>>>(svp_fea, svp_w, svp_q, ssq_svp);
  k_gemm     <<<dim3(256, BB),     256, 0, stream>>>(x, wb, qkv1);
  k_dw       <<<dim3(4, OCN, BB),  256, 0, stream>>>(qkv1, dw_w, (unsigned short*)qkv, ssq_qk);
  k_gram     <<<dim3(16, NH, BB),  256, 0, stream>>>((const unsigned short*)qkv, svp_q, Gp);
  k_attn_fold<<<dim3(NH, BB),      256, 0, stream>>>(Gp, ssq_qk, ssq_svp, temp, proj_w, W2bf);
  k_out      <<<dim3(256, BB),     256, 0, stream>>>((const unsigned short*)qkv, W2bf, outp);
}

// Round 8
// 282.669 us; speedup vs baseline: 12.8278x; 1.3827x over previous
//
#include <hip/hip_runtime.h>
#include <hip/hip_bf16.h>
#include <math.h>

#define BB   8
#define CCH  192
#define OCN  576
#define HWD  128
#define HWN  16384
#define NH   4
#define CHD  48
#define C51  51
#define GSZ  (C51*48)   // 2448 dense gram tile

typedef __hip_bfloat16 bf16;
typedef __attribute__((ext_vector_type(8))) short short8;
typedef __attribute__((ext_vector_type(4))) float f32x4;

__device__ __forceinline__ float bfbits2f(unsigned int u16) {
  union { unsigned int i; float f; } v; v.i = u16 << 16; return v.f;
}
__device__ __forceinline__ unsigned short f2bfbits(float f) {
  __hip_bfloat16 h = __float2bfloat16(f);
  return *(unsigned short*)&h;
}
__device__ __forceinline__ void stage16(const void* g, void* l) {
  __builtin_amdgcn_global_load_lds(
      (const __attribute__((address_space(1))) void*)g,
      (__attribute__((address_space(3))) void*)l, 16, 0, 0);
}

// ------- K0: svp 1x1 conv (3 -> 12) + per-block ssq partials (no atomics) ---
__global__ __launch_bounds__(256) void k_svp(
    const float* __restrict__ svp_fea, const float* __restrict__ svp_w,
    float* __restrict__ svp_q, float* __restrict__ ssq_svp_p)
{
  __shared__ float lsw[4][12];
  const int b = blockIdx.y;
  const int t = threadIdx.x;
  const int n = blockIdx.x * 256 + t;
  const int wave = t >> 6;
  const float* fb = svp_fea + (size_t)b * 3 * HWN;
  const float f0 = fb[n], f1 = fb[HWN + n], f2 = fb[2 * HWN + n];
  float* ob = svp_q + (size_t)b * 12 * HWN + n;
  #pragma unroll
  for (int r = 0; r < 12; ++r) {
    float o = svp_w[r*3]*f0 + svp_w[r*3+1]*f1 + svp_w[r*3+2]*f2;
    ob[(size_t)r * HWN] = o;
    float v = o * o;
    #pragma unroll
    for (int off = 32; off >= 1; off >>= 1) v += __shfl_down(v, off, 64);
    if ((t & 63) == 0) lsw[wave][r] = v;
  }
  __syncthreads();
  if (t < 12) {
    float s = lsw[0][t] + lsw[1][t] + lsw[2][t] + lsw[3][t];
    ssq_svp_p[((size_t)b * 12 + t) * 64 + blockIdx.x] = s;
  }
}

// ---------------- K0b: cast qkv_w (576x192 f32) -> bf16 ---------------------
__global__ __launch_bounds__(256) void k_castw(
    const float* __restrict__ w, unsigned short* __restrict__ wb)
{
  const int i = (blockIdx.x * 256 + threadIdx.x) * 4;
  float4 v = *(const float4*)(w + i);
  union { uint2 u; unsigned short s[4]; } pk;
  pk.s[0] = f2bfbits(v.x); pk.s[1] = f2bfbits(v.y);
  pk.s[2] = f2bfbits(v.z); pk.s[3] = f2bfbits(v.w);
  *(uint2*)(wb + i) = pk.u;
}

// ---------- K1: qkv1[b][576][HW] = W(bf16) @ x(f32->bf16), MFMA 16x16x32 ----
// X staged by channel-pairs: 2 float4 loads -> 4 packed ds_write_b32.
__global__ __launch_bounds__(256) void k_gemm(
    const float* __restrict__ x, const unsigned short* __restrict__ wb,
    unsigned short* __restrict__ qkv1)
{
  __shared__ unsigned short Xs[64 * CCH];
  __shared__ unsigned short Ws[96 * CCH];
  const int b = blockIdx.y;
  const int n0 = blockIdx.x * 64;
  const int t = threadIdx.x;
  const int lane = t & 63, wave = t >> 6;
  const int wm = wave >> 1, wn = wave & 1;
  const int lq = lane >> 4, lr = lane & 15;

  const float* xb = x + (size_t)b * CCH * HWN + n0;
  #pragma unroll
  for (int rr = 0; rr < 6; ++rr) {
    int idx = rr * 256 + t;
    int cp = idx >> 4, nq = idx & 15;
    int c0 = cp * 2;
    float4 v0 = *(const float4*)(xb + (size_t)c0 * HWN + nq * 4);
    float4 v1 = *(const float4*)(xb + (size_t)(c0 + 1) * HWN + nq * 4);
    int g = c0 >> 3, co = c0 & 7;
    float a0[4] = {v0.x, v0.y, v0.z, v0.w};
    float a1[4] = {v1.x, v1.y, v1.z, v1.w};
    #pragma unroll
    for (int j = 0; j < 4; ++j) {
      int n = nq * 4 + j;
      int gs = (g & ~7) | ((g & 7) ^ (n & 7) ^ ((n >> 3) & 7));
      unsigned int pk = (unsigned int)f2bfbits(a0[j])
                      | ((unsigned int)f2bfbits(a1[j]) << 16);
      *(unsigned int*)&Xs[n * CCH + gs * 8 + co] = pk;
    }
  }

  for (int mc = 0; mc < 6; ++mc) {
    const unsigned short* wsrc = wb + (size_t)mc * 96 * CCH;
    #pragma unroll
    for (int i = 0; i < 9; ++i) {
      int chunk = wave * 9 + i;
      int d = chunk * 64 + lane;
      int row = d / 24, kg = d % 24;
      int skg = (kg & ~7) | ((kg & 7) ^ (row & 7));
      stage16(wsrc + (size_t)row * CCH + skg * 8, &Ws[0] + chunk * 512);
    }
    asm volatile("s_waitcnt vmcnt(0)" ::: "memory");
    __syncthreads();

    f32x4 acc[3][2];
    #pragma unroll
    for (int mf = 0; mf < 3; ++mf)
      #pragma unroll
      for (int nf = 0; nf < 2; ++nf) acc[mf][nf] = (f32x4)0.f;

    #pragma unroll
    for (int ks = 0; ks < 6; ++ks) {
      const int gk = ks * 4 + lq;
      short8 a[3], bb[2];
      #pragma unroll
      for (int mf = 0; mf < 3; ++mf) {
        int r = wm * 48 + mf * 16 + lr;
        int sg = (gk & ~7) | ((gk & 7) ^ (r & 7));
        a[mf] = *(const short8*)&Ws[r * CCH + sg * 8];
      }
      #pragma unroll
      for (int nf = 0; nf < 2; ++nf) {
        int r = wn * 32 + nf * 16 + lr;
        int sg = (gk & ~7) | ((gk & 7) ^ (r & 7) ^ ((r >> 3) & 7));
        bb[nf] = *(const short8*)&Xs[r * CCH + sg * 8];
      }
      #pragma unroll
      for (int mf = 0; mf < 3; ++mf)
        #pragma unroll
        for (int nf = 0; nf < 2; ++nf)
          acc[mf][nf] = __builtin_amdgcn_mfma_f32_16x16x32_bf16(
              a[mf], bb[nf], acc[mf][nf], 0, 0, 0);
    }

    unsigned short* ob = qkv1 + ((size_t)b * OCN + mc * 96 + wm * 48) * HWN
                         + n0 + wn * 32;
    #pragma unroll
    for (int mf = 0; mf < 3; ++mf)
      #pragma unroll
      for (int nf = 0; nf < 2; ++nf)
        #pragma unroll
        for (int r = 0; r < 4; ++r) {
          int m = mf * 16 + lq * 4 + r;
          int n = nf * 16 + lr;
          ob[(size_t)m * HWN + n] = f2bfbits(acc[mf][nf][r]);
        }
    __syncthreads();
  }
}

// ---------- K1b: depthwise 3x3 conv, LDS-free streaming, partial ssq --------
__global__ __launch_bounds__(256) void k_dw(
    const unsigned short* __restrict__ qkv1, const float* __restrict__ dw_w,
    unsigned short* __restrict__ qkv, float* __restrict__ ssq_qk_p)
{
  __shared__ float lsw[4];
  const int b = blockIdx.z, c = blockIdx.y, slab = blockIdx.x;
  const int t = threadIdx.x;
  const int cg = t & 15, rg = t >> 4;
  const int y0 = slab * 32 + rg * 2;   // first output row
  const unsigned short* src = qkv1 + ((size_t)b * OCN + c) * HWN;
  float w[9];
  #pragma unroll
  for (int i = 0; i < 9; ++i) w[i] = dw_w[c * 9 + i];

  float rows[4][10];
  #pragma unroll
  for (int j = 0; j < 4; ++j) {
    int gr = y0 - 1 + j;
    uint4 B = make_uint4(0u, 0u, 0u, 0u);
    unsigned int Al = 0; unsigned int Cv = 0;
    if ((unsigned)gr < 128u) {
      const unsigned short* rp = src + (size_t)gr * HWD;
      B = *(const uint4*)(rp + cg * 8);
      if (cg > 0)  Al = *(const unsigned int*)(rp + cg * 8 - 2);
      if (cg < 15) Cv = (unsigned int)rp[cg * 8 + 8];
    }
    rows[j][0] = bfbits2f(Al >> 16);
    unsigned int ub[4] = {B.x, B.y, B.z, B.w};
    #pragma unroll
    for (int q = 0; q < 4; ++q) {
      rows[j][1 + 2*q] = bfbits2f(ub[q] & 0xffffu);
      rows[j][2 + 2*q] = bfbits2f(ub[q] >> 16);
    }
    rows[j][9] = bfbits2f(Cv);
  }

  unsigned short* dst = qkv + ((size_t)b * OCN + c) * HWN;
  float ssq = 0.f;
  #pragma unroll
  for (int e = 0; e < 2; ++e) {
    float acc[8];
    #pragma unroll
    for (int i = 0; i < 8; ++i) acc[i] = 0.f;
    #pragma unroll
    for (int j = 0; j < 3; ++j) {
      const float* vr = rows[e + j];
      #pragma unroll
      for (int i = 0; i < 8; ++i)
        acc[i] += w[j*3]*vr[i] + w[j*3+1]*vr[i+1] + w[j*3+2]*vr[i+2];
    }
    union { uint4 u; unsigned short s[8]; } pk;
    #pragma unroll
    for (int i = 0; i < 8; ++i) pk.s[i] = f2bfbits(acc[i]);
    *(uint4*)(dst + (size_t)(y0 + e) * HWD + cg * 8) = pk.u;
    if (c < 384) {
      #pragma unroll
      for (int i = 0; i < 8; ++i) {
        float rv = bfbits2f(pk.s[i]);
        ssq += rv * rv;
      }
    }
  }
  if (c < 384) {
    #pragma unroll
    for (int off = 32; off >= 1; off >>= 1) ssq += __shfl_down(ssq, off, 64);
    if ((t & 63) == 0) lsw[t >> 6] = ssq;
  }
  __syncthreads();
  if (c < 384 && t == 0)
    ssq_qk_p[(((size_t)b * 384 + c) << 2) | slab] =
        lsw[0] + lsw[1] + lsw[2] + lsw[3];
}

// ---------- K3: Gram partials via MFMA, direct global loads -----------------
__global__ __launch_bounds__(256) void k_gram(
    const unsigned short* __restrict__ qkv, const float* __restrict__ svp_q,
    float* __restrict__ Gp)
{
  __shared__ float Gs[C51 * 50];  // row stride 50: 2-way banks max
  const int chunk = blockIdx.x, h = blockIdx.y, b = blockIdx.z;
  const int t = threadIdx.x;
  const int lane = t & 63, wave = t >> 6;
  const int lq = lane >> 4, lr = lane & 15;
  const unsigned short* qb = qkv + ((size_t)b*OCN + h*CHD)*HWN;
  const unsigned short* kb = qkv + ((size_t)b*OCN + 192 + h*CHD)*HWN;
  const float* sb = svp_q + ((size_t)b*12 + h*3)*HWN;

  for (int idx = t; idx < C51*50; idx += 256) Gs[idx] = 0.f;

  f32x4 acc[3][3], sacc[3];
  #pragma unroll
  for (int mf = 0; mf < 3; ++mf)
    #pragma unroll
    for (int nf = 0; nf < 3; ++nf) acc[mf][nf] = (f32x4)0.f;
  #pragma unroll
  for (int nf = 0; nf < 3; ++nf) sacc[nf] = (f32x4)0.f;

  const int nbase = chunk * 1024 + wave * 256;
  #pragma unroll 4
  for (int ks = 0; ks < 8; ++ks) {
    const int n = nbase + ks * 32 + lq * 8;
    short8 a[3], bb[3];
    #pragma unroll
    for (int mf = 0; mf < 3; ++mf)
      a[mf] = *(const short8*)&qb[(size_t)(mf*16 + lr)*HWN + n];
    #pragma unroll
    for (int nf = 0; nf < 3; ++nf)
      bb[nf] = *(const short8*)&kb[(size_t)(nf*16 + lr)*HWN + n];
    union { short8 s8; unsigned short us[8]; } sv;
    #pragma unroll
    for (int i = 0; i < 8; ++i) sv.us[i] = 0;
    if (lr < 3) {
      const float* sp = sb + (size_t)lr*HWN + n;
      float4 v0 = *(const float4*)sp, v1 = *(const float4*)(sp + 4);
      sv.us[0] = f2bfbits(v0.x); sv.us[1] = f2bfbits(v0.y);
      sv.us[2] = f2bfbits(v0.z); sv.us[3] = f2bfbits(v0.w);
      sv.us[4] = f2bfbits(v1.x); sv.us[5] = f2bfbits(v1.y);
      sv.us[6] = f2bfbits(v1.z); sv.us[7] = f2bfbits(v1.w);
    }
    #pragma unroll
    for (int mf = 0; mf < 3; ++mf)
      #pragma unroll
      for (int nf = 0; nf < 3; ++nf)
        acc[mf][nf] = __builtin_amdgcn_mfma_f32_16x16x32_bf16(
            a[mf], bb[nf], acc[mf][nf], 0, 0, 0);
    #pragma unroll
    for (int nf = 0; nf < 3; ++nf)
      sacc[nf] = __builtin_amdgcn_mfma_f32_16x16x32_bf16(
          sv.s8, bb[nf], sacc[nf], 0, 0, 0);
  }

  __syncthreads();
  for (int w = 0; w < 4; ++w) {
    if (wave == w) {
      #pragma unroll
      for (int mf = 0; mf < 3; ++mf)
        #pragma unroll
        for (int nf = 0; nf < 3; ++nf)
          #pragma unroll
          for (int r = 0; r < 4; ++r)
            Gs[(mf*16 + lq*4 + r)*50 + nf*16 + lr] += acc[mf][nf][r];
      if (lq == 0) {
        #pragma unroll
        for (int nf = 0; nf < 3; ++nf)
          #pragma unroll
          for (int r = 0; r < 3; ++r)
            Gs[(48 + r)*50 + nf*16 + lr] += sacc[nf][r];
      }
    }
    __syncthreads();
  }
  float* Gout = Gp + ((size_t)((b*NH + h) * 16 + chunk)) * GSZ;
  for (int idx = t; idx < GSZ; idx += 256) {
    int row = idx / 48, col = idx - row * 48;
    Gout[idx] = Gs[row*50 + col];
  }
}

// ---- K4: reduce Gp + ssq partials; softmax; fold with proj_w -> W2 (bf16) --
__global__ __launch_bounds__(256) void k_attn_fold(
    const float* __restrict__ Gp, const float* __restrict__ ssq_qk_p,
    const float* __restrict__ ssq_svp_p, const float* __restrict__ temperature,
    const float* __restrict__ proj_w, unsigned short* __restrict__ W2bf)
{
  __shared__ float A[GSZ];
  __shared__ float qinv[C51];
  __shared__ float kinv[48];
  const int h = blockIdx.x, b = blockIdx.y;
  const int t = threadIdx.x;
  const float* Gb = Gp + ((size_t)(b*NH + h) * 16) * GSZ;
  if (t < 48) {
    const float* p = ssq_qk_p + (((size_t)b * 384 + 192 + h*48 + t) << 2);
    kinv[t] = 1.f / fmaxf(sqrtf(p[0] + p[1] + p[2] + p[3]), 1e-12f);
  }
  if (t >= 64 && t < 64 + C51) {
    int c = t - 64;
    float ss;
    if (c < 48) {
      const float* p = ssq_qk_p + (((size_t)b * 384 + h*48 + c) << 2);
      ss = p[0] + p[1] + p[2] + p[3];
    } else {
      const float* p = ssq_svp_p + ((size_t)b * 12 + h*3 + (c - 48)) * 64;
      float s0 = 0.f, s1 = 0.f, s2 = 0.f, s3 = 0.f;
      #pragma unroll
      for (int i = 0; i < 16; ++i) {
        float4 v = *(const float4*)(p + i * 4);
        s0 += v.x; s1 += v.y; s2 += v.z; s3 += v.w;
      }
      ss = (s0 + s1) + (s2 + s3);
    }
    qinv[c] = 1.f / fmaxf(sqrtf(ss), 1e-12f);
  }
  for (int idx = t; idx < GSZ; idx += 256) {
    float s = 0.f;
    #pragma unroll
    for (int c = 0; c < 16; ++c) s += Gb[(size_t)c * GSZ + idx];
    A[idx] = s;
  }
  __syncthreads();
  const float temp = temperature[h];
  if (t < C51) {
    float row[48];
    float m = -1e30f;
    const float qi = qinv[t] * temp;
    #pragma unroll
    for (int d = 0; d < 48; ++d) {
      float l = A[t*48 + d] * qi * kinv[d];
      row[d] = l; m = fmaxf(m, l);
    }
    float s = 0.f;
    #pragma unroll
    for (int d = 0; d < 48; ++d) { row[d] = expf(row[d] - m); s += row[d]; }
    const float inv = 1.f / s;
    #pragma unroll
    for (int d = 0; d < 48; ++d) A[t*48 + d] = row[d] * inv;
  }
  __syncthreads();
  for (int idx = t; idx < 192*48; idx += 256) {
    int o = idx / 48, d = idx - o*48;
    const float* pw = proj_w + o*204 + C51*h;
    float s = 0.f;
    #pragma unroll
    for (int c = 0; c < C51; ++c) s += pw[c] * A[c*48 + d];
    W2bf[((size_t)b*CCH + o)*CCH + h*48 + d] = f2bfbits(s);
  }
}

// ---------- K5: out[b] = W2b(bf16) @ v(bf16) via MFMA, fp32 out -------------
__global__ __launch_bounds__(256) void k_out(
    const unsigned short* __restrict__ qkv, const unsigned short* __restrict__ w2b,
    float* __restrict__ out)
{
  __shared__ unsigned short Vs[64 * CCH];
  __shared__ unsigned short Ws[96 * CCH];
  const int b = blockIdx.y;
  const int n0 = blockIdx.x * 64;
  const int t = threadIdx.x;
  const int lane = t & 63, wave = t >> 6;
  const int wm = wave >> 1, wn = wave & 1;
  const int lq = lane >> 4, lr = lane & 15;

  const unsigned short* vb = qkv + ((size_t)b * OCN + 384) * HWN + n0;
  #pragma unroll
  for (int rr = 0; rr < 3; ++rr) {
    int idx = rr * 256 + t;
    int cp = idx >> 3, nq = idx & 7;
    int c0 = cp * 2;
    uint4 v0 = *(const uint4*)(vb + (size_t)c0 * HWN + nq * 8);
    uint4 v1 = *(const uint4*)(vb + (size_t)(c0 + 1) * HWN + nq * 8);
    union { uint4 u; unsigned short s[8]; } p0, p1;
    p0.u = v0; p1.u = v1;
    int g = c0 >> 3, co = c0 & 7;
    #pragma unroll
    for (int j = 0; j < 8; ++j) {
      int n = nq * 8 + j;
      int gs = (g & ~7) | ((g & 7) ^ (n & 7) ^ ((n >> 3) & 7));
      unsigned int pk = (unsigned int)p0.s[j] | ((unsigned int)p1.s[j] << 16);
      *(unsigned int*)&Vs[n * CCH + gs * 8 + co] = pk;
    }
  }

  for (int mc = 0; mc < 2; ++mc) {
    const unsigned short* wsrc = w2b + ((size_t)b * CCH + mc * 96) * CCH;
    #pragma unroll
    for (int i = 0; i < 9; ++i) {
      int chunk = wave * 9 + i;
      int d = chunk * 64 + lane;
      int row = d / 24, kg = d % 24;
      int skg = (kg & ~7) | ((kg & 7) ^ (row & 7));
      stage16(wsrc + (size_t)row * CCH + skg * 8, &Ws[0] + chunk * 512);
    }
    asm volatile("s_waitcnt vmcnt(0)" ::: "memory");
    __syncthreads();

    f32x4 acc[3][2];
    #pragma unroll
    for (int mf = 0; mf < 3; ++mf)
      #pragma unroll
      for (int nf = 0; nf < 2; ++nf) acc[mf][nf] = (f32x4)0.f;

    #pragma unroll
    for (int ks = 0; ks < 6; ++ks) {
      const int gk = ks * 4 + lq;
      short8 a[3], bb[2];
      #pragma unroll
      for (int mf = 0; mf < 3; ++mf) {
        int r = wm * 48 + mf * 16 + lr;
        int sg = (gk & ~7) | ((gk & 7) ^ (r & 7));
        a[mf] = *(const short8*)&Ws[r * CCH + sg * 8];
      }
      #pragma unroll
      for (int nf = 0; nf < 2; ++nf) {
        int r = wn * 32 + nf * 16 + lr;
        int sg = (gk & ~7) | ((gk & 7) ^ (r & 7) ^ ((r >> 3) & 7));
        bb[nf] = *(const short8*)&Vs[r * CCH + sg * 8];
      }
      #pragma unroll
      for (int mf = 0; mf < 3; ++mf)
        #pragma unroll
        for (int nf = 0; nf < 2; ++nf)
          acc[mf][nf] = __builtin_amdgcn_mfma_f32_16x16x32_bf16(
              a[mf], bb[nf], acc[mf][nf], 0, 0, 0);
    }

    float* ob = out + ((size_t)b * CCH + mc * 96 + wm * 48) * HWN + n0 + wn * 32;
    #pragma unroll
    for (int mf = 0; mf < 3; ++mf)
      #pragma unroll
      for (int nf = 0; nf < 2; ++nf)
        #pragma unroll
        for (int r = 0; r < 4; ++r) {
          int m = mf * 16 + lq * 4 + r;
          int n = nf * 16 + lr;
          ob[(size_t)m * HWN + n] = acc[mf][nf][r];
        }
    __syncthreads();
  }
}

// ---------------------------------------------------------------------------
extern "C" void kernel_launch(void* const* d_in, const int* in_sizes, int n_in,
                              void* d_out, int out_size, void* d_ws, size_t ws_size,
                              hipStream_t stream)
{
  const float* x       = (const float*)d_in[0];
  const float* svp_fea = (const float*)d_in[1];
  const float* qkv_w   = (const float*)d_in[2];
  const float* dw_w    = (const float*)d_in[3];
  const float* svp_w   = (const float*)d_in[4];
  const float* proj_w  = (const float*)d_in[5];
  const float* temp    = (const float*)d_in[6];
  float* outp = (float*)d_out;

  char* ws = (char*)d_ws;
  const size_t off_qkv1   = 0;
  const size_t off_qkv    = off_qkv1  + (size_t)BB*OCN*HWN*2;
  const size_t off_wb     = off_qkv   + (size_t)BB*OCN*HWN*2;
  const size_t off_svpq   = off_wb    + (size_t)OCN*CCH*2;
  const size_t off_ssqqk  = off_svpq  + (size_t)BB*12*HWN*4;
  const size_t off_ssqsvp = off_ssqqk + (size_t)BB*384*4*4;      // partials [b][384][4]
  const size_t off_Gp     = off_ssqsvp+ (size_t)BB*12*64*4;      // partials [b][12][64]
  const size_t off_W2     = off_Gp    + (size_t)BB*NH*16*GSZ*4;  // 5.0 MB

  unsigned short* qkv1  = (unsigned short*)(ws + off_qkv1);
  bf16*  qkv     = (bf16*)(ws + off_qkv);
  unsigned short* wb    = (unsigned short*)(ws + off_wb);
  float* svp_q   = (float*)(ws + off_svpq);
  float* ssq_qk_p  = (float*)(ws + off_ssqqk);
  float* ssq_svp_p = (float*)(ws + off_ssqsvp);
  float* Gp      = (float*)(ws + off_Gp);
  unsigned short* W2bf  = (unsigned short*)(ws + off_W2);

  k_castw    <<<dim3(108),         256, 0, stream>>>(qkv_w, wb);
  k_svp      <<<dim3(64, BB),      256, 0, stream>>>(svp_fea, svp_w, svp_q, ssq_svp_p);
  k_gemm     <<<dim3(256, BB),     256, 0, stream>>>(x, wb, qkv1);
  k_dw       <<<dim3(4, OCN, BB),  256, 0, stream>>>(qkv1, dw_w, (unsigned short*)qkv, ssq_qk_p);
  k_gram     <<<dim3(16, NH, BB),  256, 0, stream>>>((const unsigned short*)qkv, svp_q, Gp);
  k_attn_fold<<<dim3(NH, BB),      256, 0, stream>>>(Gp, ssq_qk_p, ssq_svp_p, temp, proj_w, W2bf);
  k_out      <<<dim3(256, BB),     256, 0, stream>>>((const unsigned short*)qkv, W2bf, outp);
}